// Round 17
// baseline (301.990 us; speedup 1.0000x reference)
//
#include <hip/hip_runtime.h>

// ---- problem constants ----
#define D_DIM 1024
#define B_DIM 16
#define T_DIM 2048
#define M_TOT (B_DIM * T_DIM)   // 32768 rows
#define K_DIM 1024
#define LN_EPS 1e-5f
#define CHUNK 16
#define NCH (T_DIM / CHUNK)     // 128 chunks

typedef _Float16 half8 __attribute__((ext_vector_type(8)));
typedef _Float16 half4v __attribute__((ext_vector_type(4)));
typedef float f32x4 __attribute__((ext_vector_type(4)));

// ============ packed-B layout (r9/r16-validated) ============
// 16B unit index = (nf*32 + kt)*64 + lane; n = nf*16 + (lane&15),
// k = kt*32 + (lane>>4)*8. Gate frags nf 0..63; comb frags nf 64..127.

// ------- merged prep: x cvt | gate pack | W_state cvt | W_vx transpose -------
__global__ __launch_bounds__(256) void prep_all(const float* __restrict__ x,
                                                const float* __restrict__ W_in,
                                                const float* __restrict__ W_state,
                                                _Float16* __restrict__ xh,
                                                _Float16* __restrict__ pk,
                                                _Float16* __restrict__ wvxT,
                                                _Float16* __restrict__ wst) {
    __shared__ _Float16 t[32][33];
    int b = blockIdx.x, tid = threadIdx.x;
    if (b < 2048) {                      // x -> fp16, grid-stride (4M half8 units)
        int i = b * 256 + tid;
        for (; i < M_TOT * K_DIM / 8; i += 2048 * 256) {
            const float4* p = (const float4*)x + 2 * (size_t)i;
            float4 a = p[0], c = p[1];
            half8 h;
            h[0] = (_Float16)a.x; h[1] = (_Float16)a.y; h[2] = (_Float16)a.z; h[3] = (_Float16)a.w;
            h[4] = (_Float16)c.x; h[5] = (_Float16)c.y; h[6] = (_Float16)c.z; h[7] = (_Float16)c.w;
            ((half8*)xh)[i] = h;
        }
    } else if (b < 2560) {               // gate W -> packed units 0..131071
        int i = (b - 2048) * 256 + tid;
        int ll = i & 63, u = i >> 6;
        int kt = u & 31, nf = u >> 5;    // nf 0..63
        int n = nf * 16 + (ll & 15);
        int k = kt * 32 + (ll >> 4) * 8;
        const float4* s = (const float4*)&W_in[(size_t)n * 1024 + k];
        float4 a = s[0], c = s[1];
        half8 h;
        h[0] = (_Float16)a.x; h[1] = (_Float16)a.y; h[2] = (_Float16)a.z; h[3] = (_Float16)a.w;
        h[4] = (_Float16)c.x; h[5] = (_Float16)c.y; h[6] = (_Float16)c.z; h[7] = (_Float16)c.w;
        *(half8*)&pk[(size_t)i * 8] = h;
    } else if (b < 3072) {               // W_state -> wst (fp16)
        int i = (b - 2560) * 256 + tid;
        const float4* p = (const float4*)W_state + 2 * (size_t)i;
        float4 a = p[0], c = p[1];
        half8 h;
        h[0] = (_Float16)a.x; h[1] = (_Float16)a.y; h[2] = (_Float16)a.z; h[3] = (_Float16)a.w;
        h[4] = (_Float16)c.x; h[5] = (_Float16)c.y; h[6] = (_Float16)c.z; h[7] = (_Float16)c.w;
        ((half8*)wst)[i] = h;
    } else {                             // W_vx^T -> wvxT (32x32 tiles)
        int tile = b - 3072;             // 0..1023
        int bx = (tile & 31) * 32, by = (tile >> 5) * 32;
        int tx = tid & 31, ty = tid >> 5; // (32,8)
        const float* src = W_in + (size_t)D_DIM * K_DIM;
#pragma unroll
        for (int j = 0; j < 4; ++j)
            t[ty + 8 * j][tx] = (_Float16)src[(size_t)(by + ty + 8 * j) * 1024 + bx + tx];
        __syncthreads();
#pragma unroll
        for (int j = 0; j < 4; ++j)
            wvxT[(size_t)(bx + ty + 8 * j) * 1024 + by + tx] = t[tx][ty + 8 * j];
    }
}

// ---------------- async global->LDS helper ----------------
__device__ __forceinline__ void gl_lds16(const _Float16* g, _Float16* l) {
    __builtin_amdgcn_global_load_lds(
        (const __attribute__((address_space(1))) unsigned int*)g,
        (__attribute__((address_space(3))) unsigned int*)l,
        16, 0, 0);
}

// ====== 64x(128 gate + 128 comb) MFMA GEMM, 4 waves, 3 blocks/CU ======
// Occupancy lever: acc[4][4]=64 regs -> launch_bounds(256,3) = 3 waves/SIMD.
// A via 3-buffer LDS (12 KiB); B direct-to-register from L2-resident packed
// layout. Per-tile queue {A(t)[1], A(t+1)[1], bb(t)[4]} -> vmcnt(5) drains
// A(t) exactly. Epilogue fuses sigmoid + scan_pass1 (r15/r16-validated).

// Stage 64x32 A-tile (4 KiB, 256 chunks) = 1 gl_lds / thread.
__device__ __forceinline__ void stageA32(const _Float16* __restrict__ G,
                                         int row0, int kt,
                                         _Float16* lds0, int wid, int lane) {
    int c = wid * 64 + lane;            // chunk 0..255
    int rl = c >> 2;                    // row 0..63
    int cc = c & 3;
    int src = cc ^ ((rl >> 1) & 3);     // both-sides swizzle (0 conflicts)
    gl_lds16(G + (size_t)(row0 + rl) * 1024 + kt + src * 8,
             lds0 + (size_t)(wid * 64) * 8);
}

// Fragment read with matching XOR (conflict-free, measured r7..r16).
__device__ __forceinline__ half8 frag32(const _Float16* base, int row, int kq) {
    int cc = kq ^ ((row >> 1) & 3);
    return *(const half8*)(base + (size_t)row * 32 + cc * 8);
}

// B-frag: one coalesced 16B load per lane from packed layout (L2-resident)
__device__ __forceinline__ half8 bload(const _Float16* __restrict__ pb,
                                       int nf, int kt, int lane) {
    return *(const half8*)(pb + (((size_t)nf * 32 + kt) * 64 + lane) * 8);
}

template <int TA>
__device__ __forceinline__ void gstep(const _Float16* __restrict__ A,
                                      const _Float16* __restrict__ pb,
                                      int m0, int nf0, int t, int nkt,
                                      int wid, int lane, int r, int kq,
                                      _Float16 (&As)[3][64][32],
                                      half8 (&bb)[4],
                                      f32x4 (&acc)[4][4]) {
    half8 ra[4];

    // ---- tile top: own vmcnt lands A(t) ; barrier publishes all waves' A(t) ----
    if (t + 1 < nkt) asm volatile("s_waitcnt vmcnt(5)" ::: "memory");
    else             asm volatile("s_waitcnt vmcnt(0)" ::: "memory");
    __builtin_amdgcn_s_barrier();
    __builtin_amdgcn_sched_barrier(0);       // pin reads below barrier (rule #18)

    // ---- ds ra ; stage A(t+2) ; MFMA x16 ; late bb(t+1) ; end barrier ----
#pragma unroll
    for (int mi = 0; mi < 4; mi++) ra[mi] = frag32(&As[TA][0][0], mi * 16 + r, kq);
    if (t + 2 < nkt) stageA32(A, m0, (t + 2) << 5, &As[(TA + 2) % 3][0][0], wid, lane);
    __builtin_amdgcn_s_setprio(1);
#pragma unroll
    for (int mi = 0; mi < 4; mi++)
#pragma unroll
        for (int ni = 0; ni < 4; ni++)
            acc[mi][ni] = __builtin_amdgcn_mfma_f32_16x16x32_f16(ra[mi], bb[ni], acc[mi][ni], 0, 0, 0);
    __builtin_amdgcn_s_setprio(0);
    if (t + 1 < nkt) {
        bb[0] = bload(pb, nf0,      t + 1, lane);
        bb[1] = bload(pb, nf0 + 1,  t + 1, lane);
        bb[2] = bload(pb, nf0 + 64, t + 1, lane);
        bb[3] = bload(pb, nf0 + 65, t + 1, lane);
    }
    __builtin_amdgcn_s_barrier();            // A reads consumed -> restage safe
}

__global__ __launch_bounds__(256, 3) void gemm256(const _Float16* __restrict__ A,
                                                  const _Float16* __restrict__ pk,
                                                  _Float16* __restrict__ out_u,
                                                  _Float16* __restrict__ out_c,
                                                  float* __restrict__ Ac,
                                                  float* __restrict__ Bc) {
    __shared__ _Float16 As[3][64][32];    // 12 KiB (A only; B bypasses LDS)

    int bid = blockIdx.x;                 // 4096 blocks
    int xcd = bid & 7, lin = bid >> 3;    // 512 blocks/XCD
    int mt = xcd * 64 + (lin >> 3);       // 64 mt x 8 nt per XCD (x panel reused 8x)
    int nt = lin & 7;                     // 128-col pair (gate + comb)
    int m0 = mt * 64;

    int tid = threadIdx.x, wid = tid >> 6, lane = tid & 63;
    int wc = wid;                          // wave owns 32 paired cols
    int r = lane & 15, kq = lane >> 4;
    int nf0 = nt * 8 + wc * 2;             // packed gate-frag base for this wave

    f32x4 acc[4][4];
#pragma unroll
    for (int i = 0; i < 4; i++)
#pragma unroll
        for (int j = 0; j < 4; j++) acc[i][j] = (f32x4)0.f;

    half8 bb[4];
    const int nkt = K_DIM >> 5;            // 32 K-tiles

    // ---- prologue: stage A(0),A(1) ; load bb(0) ; loop-top vmcnt handles wait ----
    stageA32(A, m0, 0,  &As[0][0][0], wid, lane);
    stageA32(A, m0, 32, &As[1][0][0], wid, lane);
    bb[0] = bload(pk, nf0,      0, lane);
    bb[1] = bload(pk, nf0 + 1,  0, lane);
    bb[2] = bload(pk, nf0 + 64, 0, lane);
    bb[3] = bload(pk, nf0 + 65, 0, lane);

    for (int t0 = 0; t0 < nkt; t0 += 3) {
        gstep<0>(A, pk, m0, nf0, t0, nkt, wid, lane, r, kq, As, bb, acc);
        if (t0 + 1 < nkt)
            gstep<1>(A, pk, m0, nf0, t0 + 1, nkt, wid, lane, r, kq, As, bb, acc);
        if (t0 + 2 < nkt)
            gstep<2>(A, pk, m0, nf0, t0 + 2, nkt, wid, lane, r, kq, As, bb, acc);
    }

    // ---- epilogue: write u/cand fp16 AND per-16-row affine segments (pass1) ----
    // C/D layout: col = lane&15 (=r), row = kq*4 + q (+ mi*16). t_local = kq*4+q.
    int rr = kq * 4;
#pragma unroll
    for (int mi = 0; mi < 4; mi++) {
        int mbase = m0 + mi * 16 + rr;
        float Aab[2] = {1.f, 1.f}, Bab[2] = {0.f, 0.f};
#pragma unroll
        for (int ni = 0; ni < 2; ni++) {
            int d = nt * 128 + wc * 32 + ni * 16 + r;
#pragma unroll
            for (int q = 0; q < 4; q++) {   // t ascending within lane's 4-run
                float u = 1.f / (1.f + __expf(-acc[mi][ni][q]));
                float c = acc[mi][ni + 2][q];
                size_t m = (size_t)(mbase + q);
                out_u[m * D_DIM + d] = (_Float16)u;
                out_c[m * D_DIM + d] = (_Float16)c;
                Bab[ni] = fmaf(u, Bab[ni], (1.f - u) * c);
                Aab[ni] *= u;
            }
        }
        // ordered butterfly compose across the 4 kq lanes (t-runs kq*4..+4)
#pragma unroll
        for (int ni = 0; ni < 2; ni++) {
            float Aa = Aab[ni], Bb = Bab[ni];
            float oA = __shfl_xor(Aa, 16), oB = __shfl_xor(Bb, 16);
            if (kq & 1) { Bb = fmaf(Aa, oB, Bb); Aa *= oA; }   // mine later
            else        { Bb = fmaf(oA, Bb, oB); Aa *= oA; }   // other later
            oA = __shfl_xor(Aa, 32); oB = __shfl_xor(Bb, 32);
            if (kq & 2) { Bb = fmaf(Aa, oB, Bb); Aa *= oA; }
            else        { Bb = fmaf(oA, Bb, oB); Aa *= oA; }
            if (kq == 0) {
                int d = nt * 128 + wc * 32 + ni * 16 + r;
                int bc = mt * 4 + mi;        // global 16-chunk id = b*NCH + ch
                Ac[(size_t)bc * 1024 + d] = Aa;
                Bc[(size_t)bc * 1024 + d] = Bb;
            }
        }
    }
}

// ========== split-K W_comb GEMM (128x128 tile, r2-validated structure) ==========
__global__ __launch_bounds__(256) void wcomb_splitk(const _Float16* __restrict__ A,
                                                    const _Float16* __restrict__ Bm,
                                                    float* __restrict__ part) {
    __shared__ _Float16 As[128 * 32];
    __shared__ _Float16 Bs[128 * 32];
    int bid = blockIdx.x;                 // mt + 8*nt + 64*slice
    int mt = bid & 7, nt = (bid >> 3) & 7, sl = bid >> 6;
    int m0 = mt * 128, n0 = nt * 128, kbeg = sl * 256;
    int tid = threadIdx.x, wid = tid >> 6, lane = tid & 63;
    int wr = wid >> 1, wc = wid & 1;

    f32x4 acc[4][4];
#pragma unroll
    for (int i = 0; i < 4; i++)
#pragma unroll
        for (int j = 0; j < 4; j++) acc[i][j] = (f32x4)0.f;

    int r = lane & 15, kq = lane >> 4;

    for (int kt = kbeg; kt < kbeg + 256; kt += 32) {
        __syncthreads();
#pragma unroll
        for (int j = 0; j < 2; ++j) {
            int f = j * 256 + tid;
            int row = f >> 2, kc = f & 3;
            gl_lds16(A + (size_t)(m0 + row) * 1024 + kt + kc * 8, As + (size_t)(j * 256 + wid * 64) * 8);
            gl_lds16(Bm + (size_t)(n0 + row) * 1024 + kt + kc * 8, Bs + (size_t)(j * 256 + wid * 64) * 8);
        }
        __syncthreads();
        half8 af[4], bf[4];
#pragma unroll
        for (int mi = 0; mi < 4; mi++) af[mi] = *(const half8*)&As[(wr * 64 + mi * 16 + r) * 32 + kq * 8];
#pragma unroll
        for (int ni = 0; ni < 4; ni++) bf[ni] = *(const half8*)&Bs[(wc * 64 + ni * 16 + r) * 32 + kq * 8];
#pragma unroll
        for (int mi = 0; mi < 4; mi++)
#pragma unroll
            for (int ni = 0; ni < 4; ni++)
                acc[mi][ni] = __builtin_amdgcn_mfma_f32_16x16x32_f16(af[mi], bf[ni], acc[mi][ni], 0, 0, 0);
    }

    int rr = kq * 4;
    float* pbp = part + (size_t)sl * 1048576;
#pragma unroll
    for (int mi = 0; mi < 4; mi++) {
        int mbase = m0 + wr * 64 + mi * 16 + rr;
#pragma unroll
        for (int ni = 0; ni < 4; ni++) {
            int n = n0 + wc * 64 + ni * 16 + r;
#pragma unroll
            for (int q = 0; q < 4; q++)
                pbp[(size_t)(mbase + q) * 1024 + n] = acc[mi][ni][q];
        }
    }
}

// combine 4 split-K slices -> packed comb units (nf 64..127) [r9/r16-validated]
__global__ __launch_bounds__(256) void wcomb_combine_pack(const float* __restrict__ part,
                                                          _Float16* __restrict__ pk) {
    int i = blockIdx.x * 256 + threadIdx.x;   // 0..131071 units
    int ll = i & 63, u = i >> 6;
    int kt = u & 31, nf = u >> 5;             // local nf 0..63
    int e = nf * 16 + (ll & 15);              // W_comb row
    int k = kt * 32 + (ll >> 4) * 8;
    size_t o = (size_t)e * 1024 + k;
    float s[8];
#pragma unroll
    for (int j = 0; j < 8; ++j) s[j] = 0.f;
#pragma unroll
    for (int sl = 0; sl < 4; ++sl) {
        const float4* p = (const float4*)&part[(size_t)sl * 1048576 + o];
        float4 a = p[0], c = p[1];
        s[0] += a.x; s[1] += a.y; s[2] += a.z; s[3] += a.w;
        s[4] += c.x; s[5] += c.y; s[6] += c.z; s[7] += c.w;
    }
    half8 h;
#pragma unroll
    for (int j = 0; j < 8; ++j) h[j] = (_Float16)s[j];
    *(half8*)&pk[1048576 + (size_t)i * 8] = h;   // comb half of packed array
}

// pass 2: sequential over 128 chunks; AcH0 doubles as h0 output (read-before-write)
__global__ __launch_bounds__(256) void scan_pass2(float* __restrict__ AcH0,
                                                  const float* __restrict__ Bc) {
    int idx = blockIdx.x * 256 + threadIdx.x;   // b*D + d, 16384 total
    int b = idx >> 10, d = idx & (D_DIM - 1);
    float h = 0.f;
#pragma unroll 8
    for (int ch = 0; ch < NCH; ++ch) {
        size_t k = ((size_t)(b * NCH + ch) << 10) + d;
        float a = AcH0[k];
        float bv = Bc[k];
        AcH0[k] = h;
        h = fmaf(a, h, bv);
    }
}

// ---------------- fused scan pass 3 + LayerNorm (1 wave, 16 dims/lane) ----------------
__global__ __launch_bounds__(64) void scan_ln(const _Float16* __restrict__ u,
                                              const _Float16* __restrict__ cd,
                                              const float* __restrict__ h0,
                                              const float* __restrict__ gamma,
                                              const float* __restrict__ beta,
                                              float* __restrict__ outp) {
    int bc = blockIdx.x;                // b*NCH + ch
    int b = bc >> 7, ch = bc & (NCH - 1);
    int lane = threadIdx.x;             // 0..63
    int d0 = lane * 16;
    size_t base = ((size_t)b * T_DIM + (size_t)ch * CHUNK) * D_DIM + d0;

    float g[16], be[16], h[16];
#pragma unroll
    for (int j = 0; j < 16; j += 4) {
        *(float4*)&g[j]  = *(const float4*)&gamma[d0 + j];
        *(float4*)&be[j] = *(const float4*)&beta[d0 + j];
    }
    size_t o = (size_t)bc * D_DIM + d0;
#pragma unroll
    for (int j = 0; j < 16; j += 4) *(float4*)&h[j] = *(const float4*)&h0[o + j];

    for (int t = 0; t < CHUNK; ++t) {
        size_t row = base + (size_t)t * D_DIM;
        half8 ua = *(const half8*)&u[row];
        half8 ub = *(const half8*)&u[row + 8];
        half8 ca = *(const half8*)&cd[row];
        half8 cb = *(const half8*)&cd[row + 8];
        float s = 0.f, q = 0.f;
#pragma unroll
        for (int j = 0; j < 8; ++j) {
            float ut = (float)ua[j], ct = (float)ca[j];
            h[j] = fmaf(ut, h[j] - ct, ct);
            s += h[j]; q += h[j] * h[j];
        }
#pragma unroll
        for (int j = 0; j < 8; ++j) {
            float ut = (float)ub[j], ct = (float)cb[j];
            h[8 + j] = fmaf(ut, h[8 + j] - ct, ct);
            s += h[8 + j]; q += h[8 + j] * h[8 + j];
        }
#pragma unroll
        for (int off = 32; off > 0; off >>= 1) {
            s += __shfl_xor(s, off);
            q += __shfl_xor(q, off);
        }
        float mu = s * (1.f / D_DIM);
        float var = q * (1.f / D_DIM) - mu * mu;
        float rs = rsqrtf(var + LN_EPS);
        float o16[16];
#pragma unroll
        for (int j = 0; j < 16; ++j) o16[j] = (h[j] - mu) * rs * g[j] + be[j];
#pragma unroll
        for (int j = 0; j < 16; j += 4) *(float4*)&outp[row + j] = *(float4*)&o16[j];
    }
}

extern "C" void kernel_launch(void* const* d_in, const int* in_sizes, int n_in,
                              void* d_out, int out_size, void* d_ws, size_t ws_size,
                              hipStream_t stream) {
    const float* x       = (const float*)d_in[0];
    const float* W_in    = (const float*)d_in[1];
    const float* W_state = (const float*)d_in[2];
    const float* gamma   = (const float*)d_in[3];
    const float* beta    = (const float*)d_in[4];
    float* out = (float*)d_out;

    char* w = (char*)d_ws;
    size_t off = 0;
    auto carve = [&](size_t bytes) {
        void* p = w + off;
        off += (bytes + 255) & ~(size_t)255;
        return p;
    };
    _Float16* xh   = (_Float16*)carve((size_t)M_TOT * K_DIM * 2);           // 64 MiB
    _Float16* pk   = (_Float16*)carve((size_t)2 * D_DIM * K_DIM * 2);       // 4 MiB packed W
    _Float16* uarr = (_Float16*)carve((size_t)M_TOT * D_DIM * 2);           // 64 MiB
    _Float16* cand = (_Float16*)carve((size_t)M_TOT * D_DIM * 2);           // 64 MiB
    char* scratch  = (char*)carve((size_t)16 * 1024 * 1024);                // 16 MiB shared region
    _Float16* wvxT = (_Float16*)scratch;                                    // 2 MiB (early)
    _Float16* wst  = (_Float16*)(scratch + 2 * 1024 * 1024);                // 2 MiB (early)
    float* Ac = (float*)scratch;                                            // 8 MiB (late, also h0)
    float* Bc = (float*)(scratch + 8 * 1024 * 1024);                        // 8 MiB (late)
    float* wpart = (float*)cand;   // 16 MiB fp32 partials; cand dead until main GEMM

    // 1. merged prep (x cvt | gate pack | W_state cvt | W_vx transpose)
    prep_all<<<4096, 256, 0, stream>>>(x, W_in, W_state, xh, pk, wvxT, wst);

    // 2. W_comb = W_state @ W_vx -> packed comb units  (split-K x4)
    wcomb_splitk<<<256, 256, 0, stream>>>(wst, wvxT, wpart);
    wcomb_combine_pack<<<512, 256, 0, stream>>>(wpart, pk);

    // 3. fused projection + sigmoid + scan_pass1 (B direct-from-L2, 3 blocks/CU)
    gemm256<<<4096, 256, 0, stream>>>(xh, pk, uarr, cand, Ac, Bc);

    // 4. cross-chunk scan + fused pass3/LN
    scan_pass2<<<(B_DIM * D_DIM) / 256, 256, 0, stream>>>(Ac, Bc);
    scan_ln<<<B_DIM * NCH, 64, 0, stream>>>(uarr, cand, Ac, gamma, beta, out);
}

// Round 18
// 296.947 us; speedup vs baseline: 1.0170x; 1.0170x over previous
//
#include <hip/hip_runtime.h>

// ---- problem constants ----
#define D_DIM 1024
#define B_DIM 16
#define T_DIM 2048
#define M_TOT (B_DIM * T_DIM)   // 32768 rows
#define K_DIM 1024
#define LN_EPS 1e-5f
#define CHUNK 16
#define NCH (T_DIM / CHUNK)     // 128 chunks

typedef _Float16 half8 __attribute__((ext_vector_type(8)));
typedef _Float16 half4v __attribute__((ext_vector_type(4)));
typedef float f32x4 __attribute__((ext_vector_type(4)));

// ============ packed-B layout (r9/r16-validated) ============
// 16B unit index = (nf*32 + kt)*64 + lane; n = nf*16 + (lane&15),
// k = kt*32 + (lane>>4)*8. Gate frags nf 0..63; comb frags nf 64..127.

// ------- merged prep: x cvt | gate pack | W_state cvt | W_vx transpose -------
__global__ __launch_bounds__(256) void prep_all(const float* __restrict__ x,
                                                const float* __restrict__ W_in,
                                                const float* __restrict__ W_state,
                                                _Float16* __restrict__ xh,
                                                _Float16* __restrict__ pk,
                                                _Float16* __restrict__ wvxT,
                                                _Float16* __restrict__ wst) {
    __shared__ _Float16 t[32][33];
    int b = blockIdx.x, tid = threadIdx.x;
    if (b < 2048) {                      // x -> fp16, grid-stride (4M half8 units)
        int i = b * 256 + tid;
        for (; i < M_TOT * K_DIM / 8; i += 2048 * 256) {
            const float4* p = (const float4*)x + 2 * (size_t)i;
            float4 a = p[0], c = p[1];
            half8 h;
            h[0] = (_Float16)a.x; h[1] = (_Float16)a.y; h[2] = (_Float16)a.z; h[3] = (_Float16)a.w;
            h[4] = (_Float16)c.x; h[5] = (_Float16)c.y; h[6] = (_Float16)c.z; h[7] = (_Float16)c.w;
            ((half8*)xh)[i] = h;
        }
    } else if (b < 2560) {               // gate W -> packed units 0..131071
        int i = (b - 2048) * 256 + tid;
        int ll = i & 63, u = i >> 6;
        int kt = u & 31, nf = u >> 5;    // nf 0..63
        int n = nf * 16 + (ll & 15);
        int k = kt * 32 + (ll >> 4) * 8;
        const float4* s = (const float4*)&W_in[(size_t)n * 1024 + k];
        float4 a = s[0], c = s[1];
        half8 h;
        h[0] = (_Float16)a.x; h[1] = (_Float16)a.y; h[2] = (_Float16)a.z; h[3] = (_Float16)a.w;
        h[4] = (_Float16)c.x; h[5] = (_Float16)c.y; h[6] = (_Float16)c.z; h[7] = (_Float16)c.w;
        *(half8*)&pk[(size_t)i * 8] = h;
    } else if (b < 3072) {               // W_state -> wst (fp16)
        int i = (b - 2560) * 256 + tid;
        const float4* p = (const float4*)W_state + 2 * (size_t)i;
        float4 a = p[0], c = p[1];
        half8 h;
        h[0] = (_Float16)a.x; h[1] = (_Float16)a.y; h[2] = (_Float16)a.z; h[3] = (_Float16)a.w;
        h[4] = (_Float16)c.x; h[5] = (_Float16)c.y; h[6] = (_Float16)c.z; h[7] = (_Float16)c.w;
        ((half8*)wst)[i] = h;
    } else {                             // W_vx^T -> wvxT (32x32 tiles)
        int tile = b - 3072;             // 0..1023
        int bx = (tile & 31) * 32, by = (tile >> 5) * 32;
        int tx = tid & 31, ty = tid >> 5; // (32,8)
        const float* src = W_in + (size_t)D_DIM * K_DIM;
#pragma unroll
        for (int j = 0; j < 4; ++j)
            t[ty + 8 * j][tx] = (_Float16)src[(size_t)(by + ty + 8 * j) * 1024 + bx + tx];
        __syncthreads();
#pragma unroll
        for (int j = 0; j < 4; ++j)
            wvxT[(size_t)(bx + ty + 8 * j) * 1024 + by + tx] = t[tx][ty + 8 * j];
    }
}

// ---------------- async global->LDS helper ----------------
__device__ __forceinline__ void gl_lds16(const _Float16* g, _Float16* l) {
    __builtin_amdgcn_global_load_lds(
        (const __attribute__((address_space(1))) unsigned int*)g,
        (__attribute__((address_space(3))) unsigned int*)l,
        16, 0, 0);
}

// ====== 64x(128 gate + 128 comb) MFMA GEMM, 4 waves, 3 blocks/CU (r17) ======
// Stage 64x32 A-tile (4 KiB, 256 chunks) = 1 gl_lds / thread.
__device__ __forceinline__ void stageA32(const _Float16* __restrict__ G,
                                         int row0, int kt,
                                         _Float16* lds0, int wid, int lane) {
    int c = wid * 64 + lane;            // chunk 0..255
    int rl = c >> 2;                    // row 0..63
    int cc = c & 3;
    int src = cc ^ ((rl >> 1) & 3);     // both-sides swizzle (0 conflicts)
    gl_lds16(G + (size_t)(row0 + rl) * 1024 + kt + src * 8,
             lds0 + (size_t)(wid * 64) * 8);
}

// Fragment read with matching XOR (conflict-free, measured r7..r17).
__device__ __forceinline__ half8 frag32(const _Float16* base, int row, int kq) {
    int cc = kq ^ ((row >> 1) & 3);
    return *(const half8*)(base + (size_t)row * 32 + cc * 8);
}

// B-frag: one coalesced 16B load per lane from packed layout (L2-resident)
__device__ __forceinline__ half8 bload(const _Float16* __restrict__ pb,
                                       int nf, int kt, int lane) {
    return *(const half8*)(pb + (((size_t)nf * 32 + kt) * 64 + lane) * 8);
}

template <int TA>
__device__ __forceinline__ void gstep(const _Float16* __restrict__ A,
                                      const _Float16* __restrict__ pb,
                                      int m0, int nf0, int t, int nkt,
                                      int wid, int lane, int r, int kq,
                                      _Float16 (&As)[3][64][32],
                                      half8 (&bb)[4],
                                      f32x4 (&acc)[4][4]) {
    half8 ra[4];

    // ---- tile top: own vmcnt lands A(t) ; barrier publishes all waves' A(t) ----
    if (t + 1 < nkt) asm volatile("s_waitcnt vmcnt(5)" ::: "memory");
    else             asm volatile("s_waitcnt vmcnt(0)" ::: "memory");
    __builtin_amdgcn_s_barrier();
    __builtin_amdgcn_sched_barrier(0);       // pin reads below barrier (rule #18)

    // ---- ds ra ; stage A(t+2) ; MFMA x16 ; late bb(t+1) ; end barrier ----
#pragma unroll
    for (int mi = 0; mi < 4; mi++) ra[mi] = frag32(&As[TA][0][0], mi * 16 + r, kq);
    if (t + 2 < nkt) stageA32(A, m0, (t + 2) << 5, &As[(TA + 2) % 3][0][0], wid, lane);
    __builtin_amdgcn_s_setprio(1);
#pragma unroll
    for (int mi = 0; mi < 4; mi++)
#pragma unroll
        for (int ni = 0; ni < 4; ni++)
            acc[mi][ni] = __builtin_amdgcn_mfma_f32_16x16x32_f16(ra[mi], bb[ni], acc[mi][ni], 0, 0, 0);
    __builtin_amdgcn_s_setprio(0);
    if (t + 1 < nkt) {
        bb[0] = bload(pb, nf0,      t + 1, lane);
        bb[1] = bload(pb, nf0 + 1,  t + 1, lane);
        bb[2] = bload(pb, nf0 + 64, t + 1, lane);
        bb[3] = bload(pb, nf0 + 65, t + 1, lane);
    }
    __builtin_amdgcn_s_barrier();            // A reads consumed -> restage safe
}

__global__ __launch_bounds__(256, 3) void gemm256(const _Float16* __restrict__ A,
                                                  const _Float16* __restrict__ pk,
                                                  _Float16* __restrict__ out_u,
                                                  _Float16* __restrict__ out_c,
                                                  float* __restrict__ Ac,
                                                  float* __restrict__ Bc) {
    __shared__ _Float16 As[3][64][32];    // 12 KiB (A only; B bypasses LDS)

    int bid = blockIdx.x;                 // 4096 blocks
    int xcd = bid & 7, lin = bid >> 3;    // 512 blocks/XCD
    int mt = xcd * 64 + (lin >> 3);       // 64 mt x 8 nt per XCD (x panel reused 8x)
    int nt = lin & 7;                     // 128-col pair (gate + comb)
    int m0 = mt * 64;

    int tid = threadIdx.x, wid = tid >> 6, lane = tid & 63;
    int wc = wid;                          // wave owns 32 paired cols
    int r = lane & 15, kq = lane >> 4;
    int nf0 = nt * 8 + wc * 2;             // packed gate-frag base for this wave

    f32x4 acc[4][4];
#pragma unroll
    for (int i = 0; i < 4; i++)
#pragma unroll
        for (int j = 0; j < 4; j++) acc[i][j] = (f32x4)0.f;

    half8 bb[4];
    const int nkt = K_DIM >> 5;            // 32 K-tiles

    // ---- prologue: stage A(0),A(1) ; load bb(0) ; loop-top vmcnt handles wait ----
    stageA32(A, m0, 0,  &As[0][0][0], wid, lane);
    stageA32(A, m0, 32, &As[1][0][0], wid, lane);
    bb[0] = bload(pk, nf0,      0, lane);
    bb[1] = bload(pk, nf0 + 1,  0, lane);
    bb[2] = bload(pk, nf0 + 64, 0, lane);
    bb[3] = bload(pk, nf0 + 65, 0, lane);

    for (int t0 = 0; t0 < nkt; t0 += 3) {
        gstep<0>(A, pk, m0, nf0, t0, nkt, wid, lane, r, kq, As, bb, acc);
        if (t0 + 1 < nkt)
            gstep<1>(A, pk, m0, nf0, t0 + 1, nkt, wid, lane, r, kq, As, bb, acc);
        if (t0 + 2 < nkt)
            gstep<2>(A, pk, m0, nf0, t0 + 2, nkt, wid, lane, r, kq, As, bb, acc);
    }

    // ---- epilogue: write u/cand fp16 AND per-16-row affine segments (pass1) ----
    // C/D layout: col = lane&15 (=r), row = kq*4 + q (+ mi*16). t_local = kq*4+q.
    int rr = kq * 4;
#pragma unroll
    for (int mi = 0; mi < 4; mi++) {
        int mbase = m0 + mi * 16 + rr;
        float Aab[2] = {1.f, 1.f}, Bab[2] = {0.f, 0.f};
#pragma unroll
        for (int ni = 0; ni < 2; ni++) {
            int d = nt * 128 + wc * 32 + ni * 16 + r;
#pragma unroll
            for (int q = 0; q < 4; q++) {   // t ascending within lane's 4-run
                float u = 1.f / (1.f + __expf(-acc[mi][ni][q]));
                float c = acc[mi][ni + 2][q];
                size_t m = (size_t)(mbase + q);
                out_u[m * D_DIM + d] = (_Float16)u;
                out_c[m * D_DIM + d] = (_Float16)c;
                Bab[ni] = fmaf(u, Bab[ni], (1.f - u) * c);
                Aab[ni] *= u;
            }
        }
        // ordered butterfly compose across the 4 kq lanes (t-runs kq*4..+4)
#pragma unroll
        for (int ni = 0; ni < 2; ni++) {
            float Aa = Aab[ni], Bb = Bab[ni];
            float oA = __shfl_xor(Aa, 16), oB = __shfl_xor(Bb, 16);
            if (kq & 1) { Bb = fmaf(Aa, oB, Bb); Aa *= oA; }   // mine later
            else        { Bb = fmaf(oA, Bb, oB); Aa *= oA; }   // other later
            oA = __shfl_xor(Aa, 32); oB = __shfl_xor(Bb, 32);
            if (kq & 2) { Bb = fmaf(Aa, oB, Bb); Aa *= oA; }
            else        { Bb = fmaf(oA, Bb, oB); Aa *= oA; }
            if (kq == 0) {
                int d = nt * 128 + wc * 32 + ni * 16 + r;
                int bc = mt * 4 + mi;        // global 16-chunk id = b*NCH + ch
                Ac[(size_t)bc * 1024 + d] = Aa;
                Bc[(size_t)bc * 1024 + d] = Bb;
            }
        }
    }
}

// ========== split-K W_comb GEMM (128x128 tile, r2-validated structure) ==========
__global__ __launch_bounds__(256) void wcomb_splitk(const _Float16* __restrict__ A,
                                                    const _Float16* __restrict__ Bm,
                                                    float* __restrict__ part) {
    __shared__ _Float16 As[128 * 32];
    __shared__ _Float16 Bs[128 * 32];
    int bid = blockIdx.x;                 // mt + 8*nt + 64*slice
    int mt = bid & 7, nt = (bid >> 3) & 7, sl = bid >> 6;
    int m0 = mt * 128, n0 = nt * 128, kbeg = sl * 256;
    int tid = threadIdx.x, wid = tid >> 6, lane = tid & 63;
    int wr = wid >> 1, wc = wid & 1;

    f32x4 acc[4][4];
#pragma unroll
    for (int i = 0; i < 4; i++)
#pragma unroll
        for (int j = 0; j < 4; j++) acc[i][j] = (f32x4)0.f;

    int r = lane & 15, kq = lane >> 4;

    for (int kt = kbeg; kt < kbeg + 256; kt += 32) {
        __syncthreads();
#pragma unroll
        for (int j = 0; j < 2; ++j) {
            int f = j * 256 + tid;
            int row = f >> 2, kc = f & 3;
            gl_lds16(A + (size_t)(m0 + row) * 1024 + kt + kc * 8, As + (size_t)(j * 256 + wid * 64) * 8);
            gl_lds16(Bm + (size_t)(n0 + row) * 1024 + kt + kc * 8, Bs + (size_t)(j * 256 + wid * 64) * 8);
        }
        __syncthreads();
        half8 af[4], bf[4];
#pragma unroll
        for (int mi = 0; mi < 4; mi++) af[mi] = *(const half8*)&As[(wr * 64 + mi * 16 + r) * 32 + kq * 8];
#pragma unroll
        for (int ni = 0; ni < 4; ni++) bf[ni] = *(const half8*)&Bs[(wc * 64 + ni * 16 + r) * 32 + kq * 8];
#pragma unroll
        for (int mi = 0; mi < 4; mi++)
#pragma unroll
            for (int ni = 0; ni < 4; ni++)
                acc[mi][ni] = __builtin_amdgcn_mfma_f32_16x16x32_f16(af[mi], bf[ni], acc[mi][ni], 0, 0, 0);
    }

    int rr = kq * 4;
    float* pbp = part + (size_t)sl * 1048576;
#pragma unroll
    for (int mi = 0; mi < 4; mi++) {
        int mbase = m0 + wr * 64 + mi * 16 + rr;
#pragma unroll
        for (int ni = 0; ni < 4; ni++) {
            int n = n0 + wc * 64 + ni * 16 + r;
#pragma unroll
            for (int q = 0; q < 4; q++)
                pbp[(size_t)(mbase + q) * 1024 + n] = acc[mi][ni][q];
        }
    }
}

// combine 4 split-K slices -> packed comb units (nf 64..127) [r9/r16-validated]
__global__ __launch_bounds__(256) void wcomb_combine_pack(const float* __restrict__ part,
                                                          _Float16* __restrict__ pk) {
    int i = blockIdx.x * 256 + threadIdx.x;   // 0..131071 units
    int ll = i & 63, u = i >> 6;
    int kt = u & 31, nf = u >> 5;             // local nf 0..63
    int e = nf * 16 + (ll & 15);              // W_comb row
    int k = kt * 32 + (ll >> 4) * 8;
    size_t o = (size_t)e * 1024 + k;
    float s[8];
#pragma unroll
    for (int j = 0; j < 8; ++j) s[j] = 0.f;
#pragma unroll
    for (int sl = 0; sl < 4; ++sl) {
        const float4* p = (const float4*)&part[(size_t)sl * 1048576 + o];
        float4 a = p[0], c = p[1];
        s[0] += a.x; s[1] += a.y; s[2] += a.z; s[3] += a.w;
        s[4] += c.x; s[5] += c.y; s[6] += c.z; s[7] += c.w;
    }
    half8 h;
#pragma unroll
    for (int j = 0; j < 8; ++j) h[j] = (_Float16)s[j];
    *(half8*)&pk[1048576 + (size_t)i * 8] = h;   // comb half of packed array
}

// pass 2: sequential over 128 chunks; h0 written to SEPARATE buffer (no aliasing
// -> the unroll-8 loads hoist past the stores; r17's in-place version serialized).
__global__ __launch_bounds__(256) void scan_pass2(const float* __restrict__ Ac,
                                                  const float* __restrict__ Bc,
                                                  float* __restrict__ h0w) {
    int idx = blockIdx.x * 256 + threadIdx.x;   // b*D + d, 16384 total
    int b = idx >> 10, d = idx & (D_DIM - 1);
    float h = 0.f;
#pragma unroll 8
    for (int ch = 0; ch < NCH; ++ch) {
        size_t k = ((size_t)(b * NCH + ch) << 10) + d;
        float a = Ac[k];
        float bv = Bc[k];
        h0w[k] = h;
        h = fmaf(a, h, bv);
    }
}

// ---- fused scan pass 3 + LayerNorm (1 wave, 16 dims/lane, prefetch-pipelined) ----
__global__ __launch_bounds__(64) void scan_ln(const _Float16* __restrict__ u,
                                              const _Float16* __restrict__ cd,
                                              const float* __restrict__ h0,
                                              const float* __restrict__ gamma,
                                              const float* __restrict__ beta,
                                              float* __restrict__ outp) {
    int bc = blockIdx.x;                // b*NCH + ch
    int b = bc >> 7, ch = bc & (NCH - 1);
    int lane = threadIdx.x;             // 0..63
    int d0 = lane * 16;
    size_t base = ((size_t)b * T_DIM + (size_t)ch * CHUNK) * D_DIM + d0;

    float g[16], be[16], h[16];
#pragma unroll
    for (int j = 0; j < 16; j += 4) {
        *(float4*)&g[j]  = *(const float4*)&gamma[d0 + j];
        *(float4*)&be[j] = *(const float4*)&beta[d0 + j];
    }
    size_t o = (size_t)bc * D_DIM + d0;
#pragma unroll
    for (int j = 0; j < 16; j += 4) *(float4*)&h[j] = *(const float4*)&h0[o + j];

    // prefetch t=0
    half8 ua = *(const half8*)&u[base];
    half8 ub = *(const half8*)&u[base + 8];
    half8 ca = *(const half8*)&cd[base];
    half8 cb = *(const half8*)&cd[base + 8];

#pragma unroll
    for (int t = 0; t < CHUNK; ++t) {
        // issue t+1 loads BEFORE consuming t (double-buffer: latency hides under compute)
        half8 nua, nub, nca, ncb;
        if (t + 1 < CHUNK) {
            size_t nrow = base + (size_t)(t + 1) * D_DIM;
            nua = *(const half8*)&u[nrow];
            nub = *(const half8*)&u[nrow + 8];
            nca = *(const half8*)&cd[nrow];
            ncb = *(const half8*)&cd[nrow + 8];
        }
        size_t row = base + (size_t)t * D_DIM;
        float s = 0.f, q = 0.f;
#pragma unroll
        for (int j = 0; j < 8; ++j) {
            float ut = (float)ua[j], ct = (float)ca[j];
            h[j] = fmaf(ut, h[j] - ct, ct);
            s += h[j]; q += h[j] * h[j];
        }
#pragma unroll
        for (int j = 0; j < 8; ++j) {
            float ut = (float)ub[j], ct = (float)cb[j];
            h[8 + j] = fmaf(ut, h[8 + j] - ct, ct);
            s += h[8 + j]; q += h[8 + j] * h[8 + j];
        }
#pragma unroll
        for (int off = 32; off > 0; off >>= 1) {
            s += __shfl_xor(s, off);
            q += __shfl_xor(q, off);
        }
        float mu = s * (1.f / D_DIM);
        float var = q * (1.f / D_DIM) - mu * mu;
        float rs = rsqrtf(var + LN_EPS);
        float o16[16];
#pragma unroll
        for (int j = 0; j < 16; ++j) o16[j] = (h[j] - mu) * rs * g[j] + be[j];
#pragma unroll
        for (int j = 0; j < 16; j += 4) *(float4*)&outp[row + j] = *(float4*)&o16[j];
        ua = nua; ub = nub; ca = nca; cb = ncb;
    }
}

extern "C" void kernel_launch(void* const* d_in, const int* in_sizes, int n_in,
                              void* d_out, int out_size, void* d_ws, size_t ws_size,
                              hipStream_t stream) {
    const float* x       = (const float*)d_in[0];
    const float* W_in    = (const float*)d_in[1];
    const float* W_state = (const float*)d_in[2];
    const float* gamma   = (const float*)d_in[3];
    const float* beta    = (const float*)d_in[4];
    float* out = (float*)d_out;

    char* w = (char*)d_ws;
    size_t off = 0;
    auto carve = [&](size_t bytes) {
        void* p = w + off;
        off += (bytes + 255) & ~(size_t)255;
        return p;
    };
    _Float16* xh   = (_Float16*)carve((size_t)M_TOT * K_DIM * 2);           // 64 MiB
    _Float16* pk   = (_Float16*)carve((size_t)2 * D_DIM * K_DIM * 2);       // 4 MiB packed W
    _Float16* uarr = (_Float16*)carve((size_t)M_TOT * D_DIM * 2);           // 64 MiB
    _Float16* cand = (_Float16*)carve((size_t)M_TOT * D_DIM * 2);           // 64 MiB
    char* scratch  = (char*)carve((size_t)16 * 1024 * 1024);                // 16 MiB shared region
    _Float16* wvxT = (_Float16*)scratch;                                    // 2 MiB (early)
    _Float16* wst  = (_Float16*)(scratch + 2 * 1024 * 1024);                // 2 MiB (early)
    float* Ac = (float*)scratch;                                            // 8 MiB (late)
    float* Bc = (float*)(scratch + 8 * 1024 * 1024);                        // 8 MiB (late)
    float* wpart = (float*)cand;   // 16 MiB fp32 partials; cand dead until main GEMM
    float* h0w = (float*)xh;       // 8 MiB; xh dead after gemm256

    // 1. merged prep (x cvt | gate pack | W_state cvt | W_vx transpose)
    prep_all<<<4096, 256, 0, stream>>>(x, W_in, W_state, xh, pk, wvxT, wst);

    // 2. W_comb = W_state @ W_vx -> packed comb units  (split-K x4)
    wcomb_splitk<<<256, 256, 0, stream>>>(wst, wvxT, wpart);
    wcomb_combine_pack<<<512, 256, 0, stream>>>(wpart, pk);

    // 3. fused projection + sigmoid + scan_pass1 (B direct-from-L2, 3 blocks/CU)
    gemm256<<<4096, 256, 0, stream>>>(xh, pk, uarr, cand, Ac, Bc);

    // 4. cross-chunk scan (separate h0 output) + fused pass3/LN (prefetched)
    scan_pass2<<<(B_DIM * D_DIM) / 256, 256, 0, stream>>>(Ac, Bc, h0w);
    scan_ln<<<B_DIM * NCH, 64, 0, stream>>>(uarr, cand, h0w, gamma, beta, out);
}

// Round 19
// 291.377 us; speedup vs baseline: 1.0364x; 1.0191x over previous
//
#include <hip/hip_runtime.h>

// ---- problem constants ----
#define D_DIM 1024
#define B_DIM 16
#define T_DIM 2048
#define M_TOT (B_DIM * T_DIM)   // 32768 rows
#define K_DIM 1024
#define LN_EPS 1e-5f
#define CHUNK 16
#define NCH (T_DIM / CHUNK)     // 128 chunks

typedef _Float16 half8 __attribute__((ext_vector_type(8)));
typedef _Float16 half4v __attribute__((ext_vector_type(4)));
typedef float f32x4 __attribute__((ext_vector_type(4)));

// ============ packed-B layout (r9/r16-validated) ============
// 16B unit index = (nf*32 + kt)*64 + lane; n = nf*16 + (lane&15),
// k = kt*32 + (lane>>4)*8. Gate frags nf 0..63; comb frags nf 64..127.

// ------- merged prep: x cvt | gate pack | W_state cvt | W_vx transpose -------
__global__ __launch_bounds__(256) void prep_all(const float* __restrict__ x,
                                                const float* __restrict__ W_in,
                                                const float* __restrict__ W_state,
                                                _Float16* __restrict__ xh,
                                                _Float16* __restrict__ pk,
                                                _Float16* __restrict__ wvxT,
                                                _Float16* __restrict__ wst) {
    __shared__ _Float16 t[32][33];
    int b = blockIdx.x, tid = threadIdx.x;
    if (b < 2048) {                      // x -> fp16, grid-stride (4M half8 units)
        int i = b * 256 + tid;
        for (; i < M_TOT * K_DIM / 8; i += 2048 * 256) {
            const float4* p = (const float4*)x + 2 * (size_t)i;
            float4 a = p[0], c = p[1];
            half8 h;
            h[0] = (_Float16)a.x; h[1] = (_Float16)a.y; h[2] = (_Float16)a.z; h[3] = (_Float16)a.w;
            h[4] = (_Float16)c.x; h[5] = (_Float16)c.y; h[6] = (_Float16)c.z; h[7] = (_Float16)c.w;
            ((half8*)xh)[i] = h;
        }
    } else if (b < 2560) {               // gate W -> packed units 0..131071
        int i = (b - 2048) * 256 + tid;
        int ll = i & 63, u = i >> 6;
        int kt = u & 31, nf = u >> 5;    // nf 0..63
        int n = nf * 16 + (ll & 15);
        int k = kt * 32 + (ll >> 4) * 8;
        const float4* s = (const float4*)&W_in[(size_t)n * 1024 + k];
        float4 a = s[0], c = s[1];
        half8 h;
        h[0] = (_Float16)a.x; h[1] = (_Float16)a.y; h[2] = (_Float16)a.z; h[3] = (_Float16)a.w;
        h[4] = (_Float16)c.x; h[5] = (_Float16)c.y; h[6] = (_Float16)c.z; h[7] = (_Float16)c.w;
        *(half8*)&pk[(size_t)i * 8] = h;
    } else if (b < 3072) {               // W_state -> wst (fp16)
        int i = (b - 2560) * 256 + tid;
        const float4* p = (const float4*)W_state + 2 * (size_t)i;
        float4 a = p[0], c = p[1];
        half8 h;
        h[0] = (_Float16)a.x; h[1] = (_Float16)a.y; h[2] = (_Float16)a.z; h[3] = (_Float16)a.w;
        h[4] = (_Float16)c.x; h[5] = (_Float16)c.y; h[6] = (_Float16)c.z; h[7] = (_Float16)c.w;
        ((half8*)wst)[i] = h;
    } else {                             // W_vx^T -> wvxT (32x32 tiles)
        int tile = b - 3072;             // 0..1023
        int bx = (tile & 31) * 32, by = (tile >> 5) * 32;
        int tx = tid & 31, ty = tid >> 5; // (32,8)
        const float* src = W_in + (size_t)D_DIM * K_DIM;
#pragma unroll
        for (int j = 0; j < 4; ++j)
            t[ty + 8 * j][tx] = (_Float16)src[(size_t)(by + ty + 8 * j) * 1024 + bx + tx];
        __syncthreads();
#pragma unroll
        for (int j = 0; j < 4; ++j)
            wvxT[(size_t)(bx + ty + 8 * j) * 1024 + by + tx] = t[tx][ty + 8 * j];
    }
}

// ---------------- async global->LDS helper ----------------
__device__ __forceinline__ void gl_lds16(const _Float16* g, _Float16* l) {
    __builtin_amdgcn_global_load_lds(
        (const __attribute__((address_space(1))) unsigned int*)g,
        (__attribute__((address_space(3))) unsigned int*)l,
        16, 0, 0);
}

// ====== 64-row x (128 gate + 128 comb) MFMA GEMM, BK=64/barrier-pair ======
// 4 waves, 3 blocks/CU. A via 3-buffer [64][64] LDS (24 KiB); B direct-to-reg
// from L2-resident packed layout. Halved barrier rate vs r17: per tile =
// {vmcnt(10); barrier; 8 ds_reads; stage A(t+2); 32 MFMA; bb(t+1)x8; barrier}.
// Ledger: tile-top outstanding {A(t)[2], A(t+1)[2], bb(t)[8]} -> vmcnt(10).
// mod-8 XOR swizzle: LDS[r][c] = G[r][c^(r&7)]; read chunk lc^(r&7):
// banks phys*4 -> rows 0..7 cover all 32 banks, rows 8..15 repeat (2-way=free).

// Stage 64x64 A-tile (8 KiB, 512 chunks) = 2 gl_lds / thread.
__device__ __forceinline__ void stageA64(const _Float16* __restrict__ G,
                                         int row0, int kt,
                                         _Float16* lds0, int wid, int lane) {
#pragma unroll
    for (int call = 0; call < 2; ++call) {
        int c0 = call * 256 + wid * 64;
        int c  = c0 + lane;                 // chunk 0..511
        int rl = c >> 3;                    // row 0..63 (8 chunks/row)
        int cc = c & 7;
        int src = cc ^ (rl & 7);            // both-sides swizzle
        gl_lds16(G + (size_t)(row0 + rl) * 1024 + kt + src * 8,
                 lds0 + (size_t)c0 * 8);
    }
}

// Fragment read: logical chunk lc = ksub*4 + kq, physical = lc ^ (row&7).
__device__ __forceinline__ half8 frag64(const _Float16* base, int row, int ksub, int kq) {
    int pc = ((ksub << 2) | kq) ^ (row & 7);
    return *(const half8*)(base + (size_t)row * 64 + pc * 8);
}

// B-frag: one coalesced 16B load per lane from packed layout (L2-resident)
__device__ __forceinline__ half8 bload(const _Float16* __restrict__ pb,
                                       int nf, int kt, int lane) {
    return *(const half8*)(pb + (((size_t)nf * 32 + kt) * 64 + lane) * 8);
}

template <int TA>
__device__ __forceinline__ void gstep(const _Float16* __restrict__ A,
                                      const _Float16* __restrict__ pb,
                                      int m0, int nf0, int t, int nkt,
                                      int wid, int lane, int r, int kq,
                                      _Float16 (&As)[3][64][64],
                                      half8 (&bb)[8],
                                      f32x4 (&acc)[4][4]) {
    half8 ra0[4], ra1[4];

    // ---- tile top: own vmcnt lands A(t) ; barrier publishes all waves' A(t) ----
    if (t + 1 < nkt) asm volatile("s_waitcnt vmcnt(10)" ::: "memory");
    else             asm volatile("s_waitcnt vmcnt(8)"  ::: "memory");
    __builtin_amdgcn_s_barrier();
    __builtin_amdgcn_sched_barrier(0);       // pin reads below barrier (rule #18)

    // ---- ds ra0 (ksub0) ; stage A(t+2) ; MFMA x16 (k = 2t) ----
#pragma unroll
    for (int mi = 0; mi < 4; mi++) ra0[mi] = frag64(&As[TA][0][0], mi * 16 + r, 0, kq);
    if (t + 2 < nkt) stageA64(A, m0, (t + 2) << 6, &As[(TA + 2) % 3][0][0], wid, lane);
    __builtin_amdgcn_s_setprio(1);
#pragma unroll
    for (int mi = 0; mi < 4; mi++)
#pragma unroll
        for (int ni = 0; ni < 4; ni++)
            acc[mi][ni] = __builtin_amdgcn_mfma_f32_16x16x32_f16(ra0[mi], bb[ni], acc[mi][ni], 0, 0, 0);
    __builtin_amdgcn_s_setprio(0);

    // ---- ds ra1 (ksub1) ; MFMA x16 (k = 2t+1) ; late bb(t+1) x8 ; end barrier ----
#pragma unroll
    for (int mi = 0; mi < 4; mi++) ra1[mi] = frag64(&As[TA][0][0], mi * 16 + r, 1, kq);
    __builtin_amdgcn_s_setprio(1);
#pragma unroll
    for (int mi = 0; mi < 4; mi++)
#pragma unroll
        for (int ni = 0; ni < 4; ni++)
            acc[mi][ni] = __builtin_amdgcn_mfma_f32_16x16x32_f16(ra1[mi], bb[4 + ni], acc[mi][ni], 0, 0, 0);
    __builtin_amdgcn_s_setprio(0);
    if (t + 1 < nkt) {
        int k0 = (t + 1) << 1;
        bb[0] = bload(pb, nf0,      k0,     lane);
        bb[1] = bload(pb, nf0 + 1,  k0,     lane);
        bb[2] = bload(pb, nf0 + 64, k0,     lane);
        bb[3] = bload(pb, nf0 + 65, k0,     lane);
        bb[4] = bload(pb, nf0,      k0 + 1, lane);
        bb[5] = bload(pb, nf0 + 1,  k0 + 1, lane);
        bb[6] = bload(pb, nf0 + 64, k0 + 1, lane);
        bb[7] = bload(pb, nf0 + 65, k0 + 1, lane);
    }
    __builtin_amdgcn_s_barrier();            // A reads consumed -> restage safe
}

__global__ __launch_bounds__(256, 3) void gemm256(const _Float16* __restrict__ A,
                                                  const _Float16* __restrict__ pk,
                                                  _Float16* __restrict__ out_u,
                                                  _Float16* __restrict__ out_c,
                                                  float* __restrict__ Ac,
                                                  float* __restrict__ Bc) {
    __shared__ _Float16 As[3][64][64];    // 24 KiB (A only; B bypasses LDS)

    int bid = blockIdx.x;                 // 4096 blocks
    int xcd = bid & 7, lin = bid >> 3;    // 512 blocks/XCD
    int mt = xcd * 64 + (lin >> 3);       // 64 mt x 8 nt per XCD (x panel reused 8x)
    int nt = lin & 7;                     // 128-col pair (gate + comb)
    int m0 = mt * 64;

    int tid = threadIdx.x, wid = tid >> 6, lane = tid & 63;
    int wc = wid;                          // wave owns 32 paired cols
    int r = lane & 15, kq = lane >> 4;
    int nf0 = nt * 8 + wc * 2;             // packed gate-frag base for this wave

    f32x4 acc[4][4];
#pragma unroll
    for (int i = 0; i < 4; i++)
#pragma unroll
        for (int j = 0; j < 4; j++) acc[i][j] = (f32x4)0.f;

    half8 bb[8];
    const int nkt = K_DIM >> 6;            // 16 K-tiles of BK=64

    // ---- prologue: stage A(0),A(1) ; load bb(0) ; loop-top vmcnt handles wait ----
    stageA64(A, m0, 0,  &As[0][0][0], wid, lane);
    stageA64(A, m0, 64, &As[1][0][0], wid, lane);
    bb[0] = bload(pk, nf0,      0, lane);
    bb[1] = bload(pk, nf0 + 1,  0, lane);
    bb[2] = bload(pk, nf0 + 64, 0, lane);
    bb[3] = bload(pk, nf0 + 65, 0, lane);
    bb[4] = bload(pk, nf0,      1, lane);
    bb[5] = bload(pk, nf0 + 1,  1, lane);
    bb[6] = bload(pk, nf0 + 64, 1, lane);
    bb[7] = bload(pk, nf0 + 65, 1, lane);

    for (int t0 = 0; t0 < nkt; t0 += 3) {
        gstep<0>(A, pk, m0, nf0, t0, nkt, wid, lane, r, kq, As, bb, acc);
        if (t0 + 1 < nkt)
            gstep<1>(A, pk, m0, nf0, t0 + 1, nkt, wid, lane, r, kq, As, bb, acc);
        if (t0 + 2 < nkt)
            gstep<2>(A, pk, m0, nf0, t0 + 2, nkt, wid, lane, r, kq, As, bb, acc);
    }

    // ---- epilogue: write u/cand fp16 AND per-16-row affine segments (pass1) ----
    // C/D layout: col = lane&15 (=r), row = kq*4 + q (+ mi*16). t_local = kq*4+q.
    int rr = kq * 4;
#pragma unroll
    for (int mi = 0; mi < 4; mi++) {
        int mbase = m0 + mi * 16 + rr;
        float Aab[2] = {1.f, 1.f}, Bab[2] = {0.f, 0.f};
#pragma unroll
        for (int ni = 0; ni < 2; ni++) {
            int d = nt * 128 + wc * 32 + ni * 16 + r;
#pragma unroll
            for (int q = 0; q < 4; q++) {   // t ascending within lane's 4-run
                float u = 1.f / (1.f + __expf(-acc[mi][ni][q]));
                float c = acc[mi][ni + 2][q];
                size_t m = (size_t)(mbase + q);
                out_u[m * D_DIM + d] = (_Float16)u;
                out_c[m * D_DIM + d] = (_Float16)c;
                Bab[ni] = fmaf(u, Bab[ni], (1.f - u) * c);
                Aab[ni] *= u;
            }
        }
        // ordered butterfly compose across the 4 kq lanes (t-runs kq*4..+4)
#pragma unroll
        for (int ni = 0; ni < 2; ni++) {
            float Aa = Aab[ni], Bb = Bab[ni];
            float oA = __shfl_xor(Aa, 16), oB = __shfl_xor(Bb, 16);
            if (kq & 1) { Bb = fmaf(Aa, oB, Bb); Aa *= oA; }   // mine later
            else        { Bb = fmaf(oA, Bb, oB); Aa *= oA; }   // other later
            oA = __shfl_xor(Aa, 32); oB = __shfl_xor(Bb, 32);
            if (kq & 2) { Bb = fmaf(Aa, oB, Bb); Aa *= oA; }
            else        { Bb = fmaf(oA, Bb, oB); Aa *= oA; }
            if (kq == 0) {
                int d = nt * 128 + wc * 32 + ni * 16 + r;
                int bc = mt * 4 + mi;        // global 16-chunk id = b*NCH + ch
                Ac[(size_t)bc * 1024 + d] = Aa;
                Bc[(size_t)bc * 1024 + d] = Bb;
            }
        }
    }
}

// ========== split-K W_comb GEMM (128x128 tile, r2-validated structure) ==========
__global__ __launch_bounds__(256) void wcomb_splitk(const _Float16* __restrict__ A,
                                                    const _Float16* __restrict__ Bm,
                                                    float* __restrict__ part) {
    __shared__ _Float16 As[128 * 32];
    __shared__ _Float16 Bs[128 * 32];
    int bid = blockIdx.x;                 // mt + 8*nt + 64*slice
    int mt = bid & 7, nt = (bid >> 3) & 7, sl = bid >> 6;
    int m0 = mt * 128, n0 = nt * 128, kbeg = sl * 256;
    int tid = threadIdx.x, wid = tid >> 6, lane = tid & 63;
    int wr = wid >> 1, wc = wid & 1;

    f32x4 acc[4][4];
#pragma unroll
    for (int i = 0; i < 4; i++)
#pragma unroll
        for (int j = 0; j < 4; j++) acc[i][j] = (f32x4)0.f;

    int r = lane & 15, kq = lane >> 4;

    for (int kt = kbeg; kt < kbeg + 256; kt += 32) {
        __syncthreads();
#pragma unroll
        for (int j = 0; j < 2; ++j) {
            int f = j * 256 + tid;
            int row = f >> 2, kc = f & 3;
            gl_lds16(A + (size_t)(m0 + row) * 1024 + kt + kc * 8, As + (size_t)(j * 256 + wid * 64) * 8);
            gl_lds16(Bm + (size_t)(n0 + row) * 1024 + kt + kc * 8, Bs + (size_t)(j * 256 + wid * 64) * 8);
        }
        __syncthreads();
        half8 af[4], bf[4];
#pragma unroll
        for (int mi = 0; mi < 4; mi++) af[mi] = *(const half8*)&As[(wr * 64 + mi * 16 + r) * 32 + kq * 8];
#pragma unroll
        for (int ni = 0; ni < 4; ni++) bf[ni] = *(const half8*)&Bs[(wc * 64 + ni * 16 + r) * 32 + kq * 8];
#pragma unroll
        for (int mi = 0; mi < 4; mi++)
#pragma unroll
            for (int ni = 0; ni < 4; ni++)
                acc[mi][ni] = __builtin_amdgcn_mfma_f32_16x16x32_f16(af[mi], bf[ni], acc[mi][ni], 0, 0, 0);
    }

    int rr = kq * 4;
    float* pbp = part + (size_t)sl * 1048576;
#pragma unroll
    for (int mi = 0; mi < 4; mi++) {
        int mbase = m0 + wr * 64 + mi * 16 + rr;
#pragma unroll
        for (int ni = 0; ni < 4; ni++) {
            int n = n0 + wc * 64 + ni * 16 + r;
#pragma unroll
            for (int q = 0; q < 4; q++)
                pbp[(size_t)(mbase + q) * 1024 + n] = acc[mi][ni][q];
        }
    }
}

// combine 4 split-K slices -> packed comb units (nf 64..127) [r9/r16-validated]
__global__ __launch_bounds__(256) void wcomb_combine_pack(const float* __restrict__ part,
                                                          _Float16* __restrict__ pk) {
    int i = blockIdx.x * 256 + threadIdx.x;   // 0..131071 units
    int ll = i & 63, u = i >> 6;
    int kt = u & 31, nf = u >> 5;             // local nf 0..63
    int e = nf * 16 + (ll & 15);              // W_comb row
    int k = kt * 32 + (ll >> 4) * 8;
    size_t o = (size_t)e * 1024 + k;
    float s[8];
#pragma unroll
    for (int j = 0; j < 8; ++j) s[j] = 0.f;
#pragma unroll
    for (int sl = 0; sl < 4; ++sl) {
        const float4* p = (const float4*)&part[(size_t)sl * 1048576 + o];
        float4 a = p[0], c = p[1];
        s[0] += a.x; s[1] += a.y; s[2] += a.z; s[3] += a.w;
        s[4] += c.x; s[5] += c.y; s[6] += c.z; s[7] += c.w;
    }
    half8 h;
#pragma unroll
    for (int j = 0; j < 8; ++j) h[j] = (_Float16)s[j];
    *(half8*)&pk[1048576 + (size_t)i * 8] = h;   // comb half of packed array
}

// pass 2: sequential over 128 chunks; h0 written to SEPARATE buffer (no aliasing)
__global__ __launch_bounds__(256) void scan_pass2(const float* __restrict__ Ac,
                                                  const float* __restrict__ Bc,
                                                  float* __restrict__ h0w) {
    int idx = blockIdx.x * 256 + threadIdx.x;   // b*D + d, 16384 total
    int b = idx >> 10, d = idx & (D_DIM - 1);
    float h = 0.f;
#pragma unroll 8
    for (int ch = 0; ch < NCH; ++ch) {
        size_t k = ((size_t)(b * NCH + ch) << 10) + d;
        float a = Ac[k];
        float bv = Bc[k];
        h0w[k] = h;
        h = fmaf(a, h, bv);
    }
}

// ---- fused scan pass 3 + LayerNorm (1 wave, 16 dims/lane, prefetch-pipelined) ----
__global__ __launch_bounds__(64) void scan_ln(const _Float16* __restrict__ u,
                                              const _Float16* __restrict__ cd,
                                              const float* __restrict__ h0,
                                              const float* __restrict__ gamma,
                                              const float* __restrict__ beta,
                                              float* __restrict__ outp) {
    int bc = blockIdx.x;                // b*NCH + ch
    int b = bc >> 7, ch = bc & (NCH - 1);
    int lane = threadIdx.x;             // 0..63
    int d0 = lane * 16;
    size_t base = ((size_t)b * T_DIM + (size_t)ch * CHUNK) * D_DIM + d0;

    float g[16], be[16], h[16];
#pragma unroll
    for (int j = 0; j < 16; j += 4) {
        *(float4*)&g[j]  = *(const float4*)&gamma[d0 + j];
        *(float4*)&be[j] = *(const float4*)&beta[d0 + j];
    }
    size_t o = (size_t)bc * D_DIM + d0;
#pragma unroll
    for (int j = 0; j < 16; j += 4) *(float4*)&h[j] = *(const float4*)&h0[o + j];

    // prefetch t=0
    half8 ua = *(const half8*)&u[base];
    half8 ub = *(const half8*)&u[base + 8];
    half8 ca = *(const half8*)&cd[base];
    half8 cb = *(const half8*)&cd[base + 8];

#pragma unroll
    for (int t = 0; t < CHUNK; ++t) {
        half8 nua, nub, nca, ncb;
        if (t + 1 < CHUNK) {
            size_t nrow = base + (size_t)(t + 1) * D_DIM;
            nua = *(const half8*)&u[nrow];
            nub = *(const half8*)&u[nrow + 8];
            nca = *(const half8*)&cd[nrow];
            ncb = *(const half8*)&cd[nrow + 8];
        }
        size_t row = base + (size_t)t * D_DIM;
        float s = 0.f, q = 0.f;
#pragma unroll
        for (int j = 0; j < 8; ++j) {
            float ut = (float)ua[j], ct = (float)ca[j];
            h[j] = fmaf(ut, h[j] - ct, ct);
            s += h[j]; q += h[j] * h[j];
        }
#pragma unroll
        for (int j = 0; j < 8; ++j) {
            float ut = (float)ub[j], ct = (float)cb[j];
            h[8 + j] = fmaf(ut, h[8 + j] - ct, ct);
            s += h[8 + j]; q += h[8 + j] * h[8 + j];
        }
#pragma unroll
        for (int off = 32; off > 0; off >>= 1) {
            s += __shfl_xor(s, off);
            q += __shfl_xor(q, off);
        }
        float mu = s * (1.f / D_DIM);
        float var = q * (1.f / D_DIM) - mu * mu;
        float rs = rsqrtf(var + LN_EPS);
        float o16[16];
#pragma unroll
        for (int j = 0; j < 16; ++j) o16[j] = (h[j] - mu) * rs * g[j] + be[j];
#pragma unroll
        for (int j = 0; j < 16; j += 4) *(float4*)&outp[row + j] = *(float4*)&o16[j];
        ua = nua; ub = nub; ca = nca; cb = ncb;
    }
}

extern "C" void kernel_launch(void* const* d_in, const int* in_sizes, int n_in,
                              void* d_out, int out_size, void* d_ws, size_t ws_size,
                              hipStream_t stream) {
    const float* x       = (const float*)d_in[0];
    const float* W_in    = (const float*)d_in[1];
    const float* W_state = (const float*)d_in[2];
    const float* gamma   = (const float*)d_in[3];
    const float* beta    = (const float*)d_in[4];
    float* out = (float*)d_out;

    char* w = (char*)d_ws;
    size_t off = 0;
    auto carve = [&](size_t bytes) {
        void* p = w + off;
        off += (bytes + 255) & ~(size_t)255;
        return p;
    };
    _Float16* xh   = (_Float16*)carve((size_t)M_TOT * K_DIM * 2);           // 64 MiB
    _Float16* pk   = (_Float16*)carve((size_t)2 * D_DIM * K_DIM * 2);       // 4 MiB packed W
    _Float16* uarr = (_Float16*)carve((size_t)M_TOT * D_DIM * 2);           // 64 MiB
    _Float16* cand = (_Float16*)carve((size_t)M_TOT * D_DIM * 2);           // 64 MiB
    char* scratch  = (char*)carve((size_t)16 * 1024 * 1024);                // 16 MiB shared region
    _Float16* wvxT = (_Float16*)scratch;                                    // 2 MiB (early)
    _Float16* wst  = (_Float16*)(scratch + 2 * 1024 * 1024);                // 2 MiB (early)
    float* Ac = (float*)scratch;                                            // 8 MiB (late)
    float* Bc = (float*)(scratch + 8 * 1024 * 1024);                        // 8 MiB (late)
    float* wpart = (float*)cand;   // 16 MiB fp32 partials; cand dead until main GEMM
    float* h0w = (float*)xh;       // 8 MiB; xh dead after gemm256

    // 1. merged prep (x cvt | gate pack | W_state cvt | W_vx transpose)
    prep_all<<<4096, 256, 0, stream>>>(x, W_in, W_state, xh, pk, wvxT, wst);

    // 2. W_comb = W_state @ W_vx -> packed comb units  (split-K x4)
    wcomb_splitk<<<256, 256, 0, stream>>>(wst, wvxT, wpart);
    wcomb_combine_pack<<<512, 256, 0, stream>>>(wpart, pk);

    // 3. fused projection + sigmoid + scan_pass1 (BK=64, B direct-from-L2, 3 blk/CU)
    gemm256<<<4096, 256, 0, stream>>>(xh, pk, uarr, cand, Ac, Bc);

    // 4. cross-chunk scan (separate h0 output) + fused pass3/LN (prefetched)
    scan_pass2<<<(B_DIM * D_DIM) / 256, 256, 0, stream>>>(Ac, Bc, h0w);
    scan_ln<<<B_DIM * NCH, 64, 0, stream>>>(uarr, cand, h0w, gamma, beta, out);
}

// Round 20
// 289.470 us; speedup vs baseline: 1.0433x; 1.0066x over previous
//
#include <hip/hip_runtime.h>

// ---- problem constants ----
#define D_DIM 1024
#define B_DIM 16
#define T_DIM 2048
#define M_TOT (B_DIM * T_DIM)   // 32768 rows
#define K_DIM 1024
#define LN_EPS 1e-5f
#define CHUNK 16
#define NCH (T_DIM / CHUNK)     // 128 chunks

typedef _Float16 half8 __attribute__((ext_vector_type(8)));
typedef _Float16 half4v __attribute__((ext_vector_type(4)));
typedef float f32x4 __attribute__((ext_vector_type(4)));

// ============ packed-B layout (r9/r16-validated) ============
// 16B unit index = (nf*32 + kt)*64 + lane; n = nf*16 + (lane&15),
// k = kt*32 + (lane>>4)*8. Gate frags nf 0..63; comb frags nf 64..127.

// ------- merged prep: x cvt | gate pack | W_state cvt | W_vx transpose -------
__global__ __launch_bounds__(256) void prep_all(const float* __restrict__ x,
                                                const float* __restrict__ W_in,
                                                const float* __restrict__ W_state,
                                                _Float16* __restrict__ xh,
                                                _Float16* __restrict__ pk,
                                                _Float16* __restrict__ wvxT,
                                                _Float16* __restrict__ wst) {
    __shared__ _Float16 t[32][33];
    int b = blockIdx.x, tid = threadIdx.x;
    if (b < 2048) {                      // x -> fp16, grid-stride (4M half8 units)
        int i = b * 256 + tid;
        for (; i < M_TOT * K_DIM / 8; i += 2048 * 256) {
            const float4* p = (const float4*)x + 2 * (size_t)i;
            float4 a = p[0], c = p[1];
            half8 h;
            h[0] = (_Float16)a.x; h[1] = (_Float16)a.y; h[2] = (_Float16)a.z; h[3] = (_Float16)a.w;
            h[4] = (_Float16)c.x; h[5] = (_Float16)c.y; h[6] = (_Float16)c.z; h[7] = (_Float16)c.w;
            ((half8*)xh)[i] = h;
        }
    } else if (b < 2560) {               // gate W -> packed units 0..131071
        int i = (b - 2048) * 256 + tid;
        int ll = i & 63, u = i >> 6;
        int kt = u & 31, nf = u >> 5;    // nf 0..63
        int n = nf * 16 + (ll & 15);
        int k = kt * 32 + (ll >> 4) * 8;
        const float4* s = (const float4*)&W_in[(size_t)n * 1024 + k];
        float4 a = s[0], c = s[1];
        half8 h;
        h[0] = (_Float16)a.x; h[1] = (_Float16)a.y; h[2] = (_Float16)a.z; h[3] = (_Float16)a.w;
        h[4] = (_Float16)c.x; h[5] = (_Float16)c.y; h[6] = (_Float16)c.z; h[7] = (_Float16)c.w;
        *(half8*)&pk[(size_t)i * 8] = h;
    } else if (b < 3072) {               // W_state -> wst (fp16)
        int i = (b - 2560) * 256 + tid;
        const float4* p = (const float4*)W_state + 2 * (size_t)i;
        float4 a = p[0], c = p[1];
        half8 h;
        h[0] = (_Float16)a.x; h[1] = (_Float16)a.y; h[2] = (_Float16)a.z; h[3] = (_Float16)a.w;
        h[4] = (_Float16)c.x; h[5] = (_Float16)c.y; h[6] = (_Float16)c.z; h[7] = (_Float16)c.w;
        ((half8*)wst)[i] = h;
    } else {                             // W_vx^T -> wvxT (32x32 tiles)
        int tile = b - 3072;             // 0..1023
        int bx = (tile & 31) * 32, by = (tile >> 5) * 32;
        int tx = tid & 31, ty = tid >> 5; // (32,8)
        const float* src = W_in + (size_t)D_DIM * K_DIM;
#pragma unroll
        for (int j = 0; j < 4; ++j)
            t[ty + 8 * j][tx] = (_Float16)src[(size_t)(by + ty + 8 * j) * 1024 + bx + tx];
        __syncthreads();
#pragma unroll
        for (int j = 0; j < 4; ++j)
            wvxT[(size_t)(bx + ty + 8 * j) * 1024 + by + tx] = t[tx][ty + 8 * j];
    }
}

// ---------------- async global->LDS helper ----------------
__device__ __forceinline__ void gl_lds16(const _Float16* g, _Float16* l) {
    __builtin_amdgcn_global_load_lds(
        (const __attribute__((address_space(1))) unsigned int*)g,
        (__attribute__((address_space(3))) unsigned int*)l,
        16, 0, 0);
}

// ====== 64-row x (128 gate + 128 comb) MFMA GEMM, BK=64/barrier-pair (r19) ======
// Stage 64x64 A-tile (8 KiB, 512 chunks) = 2 gl_lds / thread.
__device__ __forceinline__ void stageA64(const _Float16* __restrict__ G,
                                         int row0, int kt,
                                         _Float16* lds0, int wid, int lane) {
#pragma unroll
    for (int call = 0; call < 2; ++call) {
        int c0 = call * 256 + wid * 64;
        int c  = c0 + lane;                 // chunk 0..511
        int rl = c >> 3;                    // row 0..63 (8 chunks/row)
        int cc = c & 7;
        int src = cc ^ (rl & 7);            // both-sides swizzle
        gl_lds16(G + (size_t)(row0 + rl) * 1024 + kt + src * 8,
                 lds0 + (size_t)c0 * 8);
    }
}

// Fragment read: logical chunk lc = ksub*4 + kq, physical = lc ^ (row&7).
__device__ __forceinline__ half8 frag64(const _Float16* base, int row, int ksub, int kq) {
    int pc = ((ksub << 2) | kq) ^ (row & 7);
    return *(const half8*)(base + (size_t)row * 64 + pc * 8);
}

// B-frag: one coalesced 16B load per lane from packed layout (L2-resident)
__device__ __forceinline__ half8 bload(const _Float16* __restrict__ pb,
                                       int nf, int kt, int lane) {
    return *(const half8*)(pb + (((size_t)nf * 32 + kt) * 64 + lane) * 8);
}

template <int TA>
__device__ __forceinline__ void gstep(const _Float16* __restrict__ A,
                                      const _Float16* __restrict__ pb,
                                      int m0, int nf0, int t, int nkt,
                                      int wid, int lane, int r, int kq,
                                      _Float16 (&As)[3][64][64],
                                      half8 (&bb)[8],
                                      f32x4 (&acc)[4][4]) {
    half8 ra0[4], ra1[4];

    // ---- tile top: own vmcnt lands A(t) ; barrier publishes all waves' A(t) ----
    if (t + 1 < nkt) asm volatile("s_waitcnt vmcnt(10)" ::: "memory");
    else             asm volatile("s_waitcnt vmcnt(8)"  ::: "memory");
    __builtin_amdgcn_s_barrier();
    __builtin_amdgcn_sched_barrier(0);       // pin reads below barrier (rule #18)

    // ---- ds ra0 (ksub0) ; stage A(t+2) ; MFMA x16 (k = 2t) ----
#pragma unroll
    for (int mi = 0; mi < 4; mi++) ra0[mi] = frag64(&As[TA][0][0], mi * 16 + r, 0, kq);
    if (t + 2 < nkt) stageA64(A, m0, (t + 2) << 6, &As[(TA + 2) % 3][0][0], wid, lane);
    __builtin_amdgcn_s_setprio(1);
#pragma unroll
    for (int mi = 0; mi < 4; mi++)
#pragma unroll
        for (int ni = 0; ni < 4; ni++)
            acc[mi][ni] = __builtin_amdgcn_mfma_f32_16x16x32_f16(ra0[mi], bb[ni], acc[mi][ni], 0, 0, 0);
    __builtin_amdgcn_s_setprio(0);

    // ---- ds ra1 (ksub1) ; MFMA x16 (k = 2t+1) ; late bb(t+1) x8 ; end barrier ----
#pragma unroll
    for (int mi = 0; mi < 4; mi++) ra1[mi] = frag64(&As[TA][0][0], mi * 16 + r, 1, kq);
    __builtin_amdgcn_s_setprio(1);
#pragma unroll
    for (int mi = 0; mi < 4; mi++)
#pragma unroll
        for (int ni = 0; ni < 4; ni++)
            acc[mi][ni] = __builtin_amdgcn_mfma_f32_16x16x32_f16(ra1[mi], bb[4 + ni], acc[mi][ni], 0, 0, 0);
    __builtin_amdgcn_s_setprio(0);
    if (t + 1 < nkt) {
        int k0 = (t + 1) << 1;
        bb[0] = bload(pb, nf0,      k0,     lane);
        bb[1] = bload(pb, nf0 + 1,  k0,     lane);
        bb[2] = bload(pb, nf0 + 64, k0,     lane);
        bb[3] = bload(pb, nf0 + 65, k0,     lane);
        bb[4] = bload(pb, nf0,      k0 + 1, lane);
        bb[5] = bload(pb, nf0 + 1,  k0 + 1, lane);
        bb[6] = bload(pb, nf0 + 64, k0 + 1, lane);
        bb[7] = bload(pb, nf0 + 65, k0 + 1, lane);
    }
    __builtin_amdgcn_s_barrier();            // A reads consumed -> restage safe
}

__global__ __launch_bounds__(256, 3) void gemm256(const _Float16* __restrict__ A,
                                                  const _Float16* __restrict__ pk,
                                                  _Float16* __restrict__ out_u,
                                                  _Float16* __restrict__ out_c,
                                                  float* __restrict__ Ac,
                                                  float* __restrict__ Bc) {
    __shared__ _Float16 As[3][64][64];    // 24 KiB (A only; B bypasses LDS)

    int bid = blockIdx.x;                 // 4096 blocks
    int xcd = bid & 7, lin = bid >> 3;    // 512 blocks/XCD
    int mt = xcd * 64 + (lin >> 3);       // 64 mt x 8 nt per XCD (x panel reused 8x)
    int nt = lin & 7;                     // 128-col pair (gate + comb)
    int m0 = mt * 64;

    int tid = threadIdx.x, wid = tid >> 6, lane = tid & 63;
    int wc = wid;                          // wave owns 32 paired cols
    int r = lane & 15, kq = lane >> 4;
    int nf0 = nt * 8 + wc * 2;             // packed gate-frag base for this wave

    f32x4 acc[4][4];
#pragma unroll
    for (int i = 0; i < 4; i++)
#pragma unroll
        for (int j = 0; j < 4; j++) acc[i][j] = (f32x4)0.f;

    half8 bb[8];
    const int nkt = K_DIM >> 6;            // 16 K-tiles of BK=64

    // ---- prologue: stage A(0),A(1) ; load bb(0) ; loop-top vmcnt handles wait ----
    stageA64(A, m0, 0,  &As[0][0][0], wid, lane);
    stageA64(A, m0, 64, &As[1][0][0], wid, lane);
    bb[0] = bload(pk, nf0,      0, lane);
    bb[1] = bload(pk, nf0 + 1,  0, lane);
    bb[2] = bload(pk, nf0 + 64, 0, lane);
    bb[3] = bload(pk, nf0 + 65, 0, lane);
    bb[4] = bload(pk, nf0,      1, lane);
    bb[5] = bload(pk, nf0 + 1,  1, lane);
    bb[6] = bload(pk, nf0 + 64, 1, lane);
    bb[7] = bload(pk, nf0 + 65, 1, lane);

    for (int t0 = 0; t0 < nkt; t0 += 3) {
        gstep<0>(A, pk, m0, nf0, t0, nkt, wid, lane, r, kq, As, bb, acc);
        if (t0 + 1 < nkt)
            gstep<1>(A, pk, m0, nf0, t0 + 1, nkt, wid, lane, r, kq, As, bb, acc);
        if (t0 + 2 < nkt)
            gstep<2>(A, pk, m0, nf0, t0 + 2, nkt, wid, lane, r, kq, As, bb, acc);
    }

    // ---- epilogue: write u/cand fp16 AND per-16-row affine segments (pass1) ----
    // C/D layout: col = lane&15 (=r), row = kq*4 + q (+ mi*16). t_local = kq*4+q.
    int rr = kq * 4;
#pragma unroll
    for (int mi = 0; mi < 4; mi++) {
        int mbase = m0 + mi * 16 + rr;
        float Aab[2] = {1.f, 1.f}, Bab[2] = {0.f, 0.f};
#pragma unroll
        for (int ni = 0; ni < 2; ni++) {
            int d = nt * 128 + wc * 32 + ni * 16 + r;
#pragma unroll
            for (int q = 0; q < 4; q++) {   // t ascending within lane's 4-run
                float u = 1.f / (1.f + __expf(-acc[mi][ni][q]));
                float c = acc[mi][ni + 2][q];
                size_t m = (size_t)(mbase + q);
                out_u[m * D_DIM + d] = (_Float16)u;
                out_c[m * D_DIM + d] = (_Float16)c;
                Bab[ni] = fmaf(u, Bab[ni], (1.f - u) * c);
                Aab[ni] *= u;
            }
        }
        // ordered butterfly compose across the 4 kq lanes (t-runs kq*4..+4)
#pragma unroll
        for (int ni = 0; ni < 2; ni++) {
            float Aa = Aab[ni], Bb = Bab[ni];
            float oA = __shfl_xor(Aa, 16), oB = __shfl_xor(Bb, 16);
            if (kq & 1) { Bb = fmaf(Aa, oB, Bb); Aa *= oA; }   // mine later
            else        { Bb = fmaf(oA, Bb, oB); Aa *= oA; }   // other later
            oA = __shfl_xor(Aa, 32); oB = __shfl_xor(Bb, 32);
            if (kq & 2) { Bb = fmaf(Aa, oB, Bb); Aa *= oA; }
            else        { Bb = fmaf(oA, Bb, oB); Aa *= oA; }
            if (kq == 0) {
                int d = nt * 128 + wc * 32 + ni * 16 + r;
                int bc = mt * 4 + mi;        // global 16-chunk id = b*NCH + ch
                Ac[(size_t)bc * 1024 + d] = Aa;
                Bc[(size_t)bc * 1024 + d] = Bb;
            }
        }
    }
}

// ========== split-K W_comb GEMM (128x128 tile, r2-validated structure) ==========
__global__ __launch_bounds__(256) void wcomb_splitk(const _Float16* __restrict__ A,
                                                    const _Float16* __restrict__ Bm,
                                                    float* __restrict__ part) {
    __shared__ _Float16 As[128 * 32];
    __shared__ _Float16 Bs[128 * 32];
    int bid = blockIdx.x;                 // mt + 8*nt + 64*slice
    int mt = bid & 7, nt = (bid >> 3) & 7, sl = bid >> 6;
    int m0 = mt * 128, n0 = nt * 128, kbeg = sl * 256;
    int tid = threadIdx.x, wid = tid >> 6, lane = tid & 63;
    int wr = wid >> 1, wc = wid & 1;

    f32x4 acc[4][4];
#pragma unroll
    for (int i = 0; i < 4; i++)
#pragma unroll
        for (int j = 0; j < 4; j++) acc[i][j] = (f32x4)0.f;

    int r = lane & 15, kq = lane >> 4;

    for (int kt = kbeg; kt < kbeg + 256; kt += 32) {
        __syncthreads();
#pragma unroll
        for (int j = 0; j < 2; ++j) {
            int f = j * 256 + tid;
            int row = f >> 2, kc = f & 3;
            gl_lds16(A + (size_t)(m0 + row) * 1024 + kt + kc * 8, As + (size_t)(j * 256 + wid * 64) * 8);
            gl_lds16(Bm + (size_t)(n0 + row) * 1024 + kt + kc * 8, Bs + (size_t)(j * 256 + wid * 64) * 8);
        }
        __syncthreads();
        half8 af[4], bf[4];
#pragma unroll
        for (int mi = 0; mi < 4; mi++) af[mi] = *(const half8*)&As[(wr * 64 + mi * 16 + r) * 32 + kq * 8];
#pragma unroll
        for (int ni = 0; ni < 4; ni++) bf[ni] = *(const half8*)&Bs[(wc * 64 + ni * 16 + r) * 32 + kq * 8];
#pragma unroll
        for (int mi = 0; mi < 4; mi++)
#pragma unroll
            for (int ni = 0; ni < 4; ni++)
                acc[mi][ni] = __builtin_amdgcn_mfma_f32_16x16x32_f16(af[mi], bf[ni], acc[mi][ni], 0, 0, 0);
    }

    int rr = kq * 4;
    float* pbp = part + (size_t)sl * 1048576;
#pragma unroll
    for (int mi = 0; mi < 4; mi++) {
        int mbase = m0 + wr * 64 + mi * 16 + rr;
#pragma unroll
        for (int ni = 0; ni < 4; ni++) {
            int n = n0 + wc * 64 + ni * 16 + r;
#pragma unroll
            for (int q = 0; q < 4; q++)
                pbp[(size_t)(mbase + q) * 1024 + n] = acc[mi][ni][q];
        }
    }
}

// combine 4 split-K slices -> packed comb units (nf 64..127) [r9/r16-validated]
__global__ __launch_bounds__(256) void wcomb_combine_pack(const float* __restrict__ part,
                                                          _Float16* __restrict__ pk) {
    int i = blockIdx.x * 256 + threadIdx.x;   // 0..131071 units
    int ll = i & 63, u = i >> 6;
    int kt = u & 31, nf = u >> 5;             // local nf 0..63
    int e = nf * 16 + (ll & 15);              // W_comb row
    int k = kt * 32 + (ll >> 4) * 8;
    size_t o = (size_t)e * 1024 + k;
    float s[8];
#pragma unroll
    for (int j = 0; j < 8; ++j) s[j] = 0.f;
#pragma unroll
    for (int sl = 0; sl < 4; ++sl) {
        const float4* p = (const float4*)&part[(size_t)sl * 1048576 + o];
        float4 a = p[0], c = p[1];
        s[0] += a.x; s[1] += a.y; s[2] += a.z; s[3] += a.w;
        s[4] += c.x; s[5] += c.y; s[6] += c.z; s[7] += c.w;
    }
    half8 h;
#pragma unroll
    for (int j = 0; j < 8; ++j) h[j] = (_Float16)s[j];
    *(half8*)&pk[1048576 + (size_t)i * 8] = h;   // comb half of packed array
}

// pass 2: sequential over 128 chunks; 64-thread blocks x 256 -> all CUs active.
__global__ __launch_bounds__(64) void scan_pass2(const float* __restrict__ Ac,
                                                 const float* __restrict__ Bc,
                                                 float* __restrict__ h0w) {
    int idx = blockIdx.x * 64 + threadIdx.x;    // b*D + d, 16384 total
    int b = idx >> 10, d = idx & (D_DIM - 1);
    float h = 0.f;
#pragma unroll 8
    for (int ch = 0; ch < NCH; ++ch) {
        size_t k = ((size_t)(b * NCH + ch) << 10) + d;
        float a = Ac[k];
        float bv = Bc[k];
        h0w[k] = h;
        h = fmaf(a, h, bv);
    }
}

// ---- fused scan pass 3 + LayerNorm (1 wave, 16 dims/lane, depth-2 prefetch) ----
__global__ __launch_bounds__(64) void scan_ln(const _Float16* __restrict__ u,
                                              const _Float16* __restrict__ cd,
                                              const float* __restrict__ h0,
                                              const float* __restrict__ gamma,
                                              const float* __restrict__ beta,
                                              float* __restrict__ outp) {
    int bc = blockIdx.x;                // b*NCH + ch
    int b = bc >> 7, ch = bc & (NCH - 1);
    int lane = threadIdx.x;             // 0..63
    int d0 = lane * 16;
    size_t base = ((size_t)b * T_DIM + (size_t)ch * CHUNK) * D_DIM + d0;

    float g[16], be[16], h[16];
#pragma unroll
    for (int j = 0; j < 16; j += 4) {
        *(float4*)&g[j]  = *(const float4*)&gamma[d0 + j];
        *(float4*)&be[j] = *(const float4*)&beta[d0 + j];
    }
    size_t o = (size_t)bc * D_DIM + d0;
#pragma unroll
    for (int j = 0; j < 16; j += 4) *(float4*)&h[j] = *(const float4*)&h0[o + j];

    // depth-2 prefetch: even set (rows 0,2,..) and odd set (rows 1,3,..)
    half8 ua0 = *(const half8*)&u[base];
    half8 ub0 = *(const half8*)&u[base + 8];
    half8 ca0 = *(const half8*)&cd[base];
    half8 cb0 = *(const half8*)&cd[base + 8];
    half8 ua1 = *(const half8*)&u[base + D_DIM];
    half8 ub1 = *(const half8*)&u[base + D_DIM + 8];
    half8 ca1 = *(const half8*)&cd[base + D_DIM];
    half8 cb1 = *(const half8*)&cd[base + D_DIM + 8];

#pragma unroll
    for (int t = 0; t < CHUNK; t += 2) {
        half8 nua0, nub0, nca0, ncb0, nua1, nub1, nca1, ncb1;
        if (t + 2 < CHUNK) {
            size_t nrow = base + (size_t)(t + 2) * D_DIM;
            nua0 = *(const half8*)&u[nrow];
            nub0 = *(const half8*)&u[nrow + 8];
            nca0 = *(const half8*)&cd[nrow];
            ncb0 = *(const half8*)&cd[nrow + 8];
        }
        if (t + 3 < CHUNK) {
            size_t nrow = base + (size_t)(t + 3) * D_DIM;
            nua1 = *(const half8*)&u[nrow];
            nub1 = *(const half8*)&u[nrow + 8];
            nca1 = *(const half8*)&cd[nrow];
            ncb1 = *(const half8*)&cd[nrow + 8];
        }
        // ---- row t (even set) ----
        {
            size_t row = base + (size_t)t * D_DIM;
            float s = 0.f, q = 0.f;
#pragma unroll
            for (int j = 0; j < 8; ++j) {
                float ut = (float)ua0[j], ct = (float)ca0[j];
                h[j] = fmaf(ut, h[j] - ct, ct);
                s += h[j]; q += h[j] * h[j];
            }
#pragma unroll
            for (int j = 0; j < 8; ++j) {
                float ut = (float)ub0[j], ct = (float)cb0[j];
                h[8 + j] = fmaf(ut, h[8 + j] - ct, ct);
                s += h[8 + j]; q += h[8 + j] * h[8 + j];
            }
#pragma unroll
            for (int off = 32; off > 0; off >>= 1) {
                s += __shfl_xor(s, off);
                q += __shfl_xor(q, off);
            }
            float mu = s * (1.f / D_DIM);
            float var = q * (1.f / D_DIM) - mu * mu;
            float rs = rsqrtf(var + LN_EPS);
            float o16[16];
#pragma unroll
            for (int j = 0; j < 16; ++j) o16[j] = (h[j] - mu) * rs * g[j] + be[j];
#pragma unroll
            for (int j = 0; j < 16; j += 4) *(float4*)&outp[row + j] = *(float4*)&o16[j];
        }
        // ---- row t+1 (odd set) ----
        {
            size_t row = base + (size_t)(t + 1) * D_DIM;
            float s = 0.f, q = 0.f;
#pragma unroll
            for (int j = 0; j < 8; ++j) {
                float ut = (float)ua1[j], ct = (float)ca1[j];
                h[j] = fmaf(ut, h[j] - ct, ct);
                s += h[j]; q += h[j] * h[j];
            }
#pragma unroll
            for (int j = 0; j < 8; ++j) {
                float ut = (float)ub1[j], ct = (float)cb1[j];
                h[8 + j] = fmaf(ut, h[8 + j] - ct, ct);
                s += h[8 + j]; q += h[8 + j] * h[8 + j];
            }
#pragma unroll
            for (int off = 32; off > 0; off >>= 1) {
                s += __shfl_xor(s, off);
                q += __shfl_xor(q, off);
            }
            float mu = s * (1.f / D_DIM);
            float var = q * (1.f / D_DIM) - mu * mu;
            float rs = rsqrtf(var + LN_EPS);
            float o16[16];
#pragma unroll
            for (int j = 0; j < 16; ++j) o16[j] = (h[j] - mu) * rs * g[j] + be[j];
#pragma unroll
            for (int j = 0; j < 16; j += 4) *(float4*)&outp[row + j] = *(float4*)&o16[j];
        }
        ua0 = nua0; ub0 = nub0; ca0 = nca0; cb0 = ncb0;
        ua1 = nua1; ub1 = nub1; ca1 = nca1; cb1 = ncb1;
    }
}

extern "C" void kernel_launch(void* const* d_in, const int* in_sizes, int n_in,
                              void* d_out, int out_size, void* d_ws, size_t ws_size,
                              hipStream_t stream) {
    const float* x       = (const float*)d_in[0];
    const float* W_in    = (const float*)d_in[1];
    const float* W_state = (const float*)d_in[2];
    const float* gamma   = (const float*)d_in[3];
    const float* beta    = (const float*)d_in[4];
    float* out = (float*)d_out;

    char* w = (char*)d_ws;
    size_t off = 0;
    auto carve = [&](size_t bytes) {
        void* p = w + off;
        off += (bytes + 255) & ~(size_t)255;
        return p;
    };
    _Float16* xh   = (_Float16*)carve((size_t)M_TOT * K_DIM * 2);           // 64 MiB
    _Float16* pk   = (_Float16*)carve((size_t)2 * D_DIM * K_DIM * 2);       // 4 MiB packed W
    _Float16* uarr = (_Float16*)carve((size_t)M_TOT * D_DIM * 2);           // 64 MiB
    _Float16* cand = (_Float16*)carve((size_t)M_TOT * D_DIM * 2);           // 64 MiB
    char* scratch  = (char*)carve((size_t)16 * 1024 * 1024);                // 16 MiB shared region
    _Float16* wvxT = (_Float16*)scratch;                                    // 2 MiB (early)
    _Float16* wst  = (_Float16*)(scratch + 2 * 1024 * 1024);                // 2 MiB (early)
    float* Ac = (float*)scratch;                                            // 8 MiB (late)
    float* Bc = (float*)(scratch + 8 * 1024 * 1024);                        // 8 MiB (late)
    float* wpart = (float*)cand;   // 16 MiB fp32 partials; cand dead until main GEMM
    float* h0w = (float*)xh;       // 8 MiB; xh dead after gemm256

    // 1. merged prep (x cvt | gate pack | W_state cvt | W_vx transpose)
    prep_all<<<4096, 256, 0, stream>>>(x, W_in, W_state, xh, pk, wvxT, wst);

    // 2. W_comb = W_state @ W_vx -> packed comb units  (split-K x4)
    wcomb_splitk<<<256, 256, 0, stream>>>(wst, wvxT, wpart);
    wcomb_combine_pack<<<512, 256, 0, stream>>>(wpart, pk);

    // 3. fused projection + sigmoid + scan_pass1 (BK=64, B direct-from-L2, 3 blk/CU)
    gemm256<<<4096, 256, 0, stream>>>(xh, pk, uarr, cand, Ac, Bc);

    // 4. cross-chunk scan (all-CU spread) + fused pass3/LN (depth-2 prefetch)
    scan_pass2<<<(B_DIM * D_DIM) / 64, 64, 0, stream>>>(Ac, Bc, h0w);
    scan_ln<<<B_DIM * NCH, 64, 0, stream>>>(uarr, cand, h0w, gamma, beta, out);
}

// Round 21
// 282.628 us; speedup vs baseline: 1.0685x; 1.0242x over previous
//
#include <hip/hip_runtime.h>

// ---- problem constants ----
#define D_DIM 1024
#define B_DIM 16
#define T_DIM 2048
#define M_TOT (B_DIM * T_DIM)   // 32768 rows
#define K_DIM 1024
#define LN_EPS 1e-5f
#define CHUNK 16
#define NCH (T_DIM / CHUNK)     // 128 chunks

typedef _Float16 half8 __attribute__((ext_vector_type(8)));
typedef _Float16 half4v __attribute__((ext_vector_type(4)));
typedef float f32x4 __attribute__((ext_vector_type(4)));

// ============ packed-B layout (r9/r16-validated) ============
// 16B unit index = (nf*32 + kt)*64 + lane; n = nf*16 + (lane&15),
// k = kt*32 + (lane>>4)*8. Gate frags nf 0..63; comb frags nf 64..127.

// ------- merged prep: x cvt | gate pack | W_state cvt | W_vx transpose -------
__global__ __launch_bounds__(256) void prep_all(const float* __restrict__ x,
                                                const float* __restrict__ W_in,
                                                const float* __restrict__ W_state,
                                                _Float16* __restrict__ xh,
                                                _Float16* __restrict__ pk,
                                                _Float16* __restrict__ wvxT,
                                                _Float16* __restrict__ wst) {
    __shared__ _Float16 t[32][33];
    int b = blockIdx.x, tid = threadIdx.x;
    if (b < 2048) {                      // x -> fp16, grid-stride (4M half8 units)
        int i = b * 256 + tid;
        for (; i < M_TOT * K_DIM / 8; i += 2048 * 256) {
            const float4* p = (const float4*)x + 2 * (size_t)i;
            float4 a = p[0], c = p[1];
            half8 h;
            h[0] = (_Float16)a.x; h[1] = (_Float16)a.y; h[2] = (_Float16)a.z; h[3] = (_Float16)a.w;
            h[4] = (_Float16)c.x; h[5] = (_Float16)c.y; h[6] = (_Float16)c.z; h[7] = (_Float16)c.w;
            ((half8*)xh)[i] = h;
        }
    } else if (b < 2560) {               // gate W -> packed units 0..131071
        int i = (b - 2048) * 256 + tid;
        int ll = i & 63, u = i >> 6;
        int kt = u & 31, nf = u >> 5;    // nf 0..63
        int n = nf * 16 + (ll & 15);
        int k = kt * 32 + (ll >> 4) * 8;
        const float4* s = (const float4*)&W_in[(size_t)n * 1024 + k];
        float4 a = s[0], c = s[1];
        half8 h;
        h[0] = (_Float16)a.x; h[1] = (_Float16)a.y; h[2] = (_Float16)a.z; h[3] = (_Float16)a.w;
        h[4] = (_Float16)c.x; h[5] = (_Float16)c.y; h[6] = (_Float16)c.z; h[7] = (_Float16)c.w;
        *(half8*)&pk[(size_t)i * 8] = h;
    } else if (b < 3072) {               // W_state -> wst (fp16)
        int i = (b - 2560) * 256 + tid;
        const float4* p = (const float4*)W_state + 2 * (size_t)i;
        float4 a = p[0], c = p[1];
        half8 h;
        h[0] = (_Float16)a.x; h[1] = (_Float16)a.y; h[2] = (_Float16)a.z; h[3] = (_Float16)a.w;
        h[4] = (_Float16)c.x; h[5] = (_Float16)c.y; h[6] = (_Float16)c.z; h[7] = (_Float16)c.w;
        ((half8*)wst)[i] = h;
    } else {                             // W_vx^T -> wvxT (32x32 tiles)
        int tile = b - 3072;             // 0..1023
        int bx = (tile & 31) * 32, by = (tile >> 5) * 32;
        int tx = tid & 31, ty = tid >> 5; // (32,8)
        const float* src = W_in + (size_t)D_DIM * K_DIM;
#pragma unroll
        for (int j = 0; j < 4; ++j)
            t[ty + 8 * j][tx] = (_Float16)src[(size_t)(by + ty + 8 * j) * 1024 + bx + tx];
        __syncthreads();
#pragma unroll
        for (int j = 0; j < 4; ++j)
            wvxT[(size_t)(bx + ty + 8 * j) * 1024 + by + tx] = t[tx][ty + 8 * j];
    }
}

// ---------------- async global->LDS helper ----------------
__device__ __forceinline__ void gl_lds16(const _Float16* g, _Float16* l) {
    __builtin_amdgcn_global_load_lds(
        (const __attribute__((address_space(1))) unsigned int*)g,
        (__attribute__((address_space(3))) unsigned int*)l,
        16, 0, 0);
}

// ====== 128-row x (128 gate + 128 comb) MFMA GEMM, BK=64, 2 blocks/CU ======
// 64 MFMA per barrier-pair per wave (2x r19). A via 3-buffer [128][64] LDS
// (48 KiB); B direct-to-reg from L2-resident packed layout.
// Ledger: tile-top outstanding {A(t+1)[4], bb(t)[8]} -> vmcnt(12); A(t) is
// provably older than bb(t-1) whose register deps already drained it.
// mod-8 XOR swizzle: LDS[r][c] = G[r][c^(r&7)]; read chunk lc^(r&7) (2-way=free).

// Stage 128x64 A-tile (16 KiB, 1024 chunks) = 4 gl_lds / thread.
__device__ __forceinline__ void stageA64(const _Float16* __restrict__ G,
                                         int row0, int kt,
                                         _Float16* lds0, int wid, int lane) {
#pragma unroll
    for (int call = 0; call < 4; ++call) {
        int c0 = call * 256 + wid * 64;
        int c  = c0 + lane;                 // chunk 0..1023
        int rl = c >> 3;                    // row 0..127 (8 chunks/row)
        int cc = c & 7;
        int src = cc ^ (rl & 7);            // both-sides swizzle
        gl_lds16(G + (size_t)(row0 + rl) * 1024 + kt + src * 8,
                 lds0 + (size_t)c0 * 8);
    }
}

// Fragment read: logical chunk lc = ksub*4 + kq, physical = lc ^ (row&7).
__device__ __forceinline__ half8 frag64(const _Float16* base, int row, int ksub, int kq) {
    int pc = ((ksub << 2) | kq) ^ (row & 7);
    return *(const half8*)(base + (size_t)row * 64 + pc * 8);
}

// B-frag: one coalesced 16B load per lane from packed layout (L2-resident)
__device__ __forceinline__ half8 bload(const _Float16* __restrict__ pb,
                                       int nf, int kt, int lane) {
    return *(const half8*)(pb + (((size_t)nf * 32 + kt) * 64 + lane) * 8);
}

template <int TA>
__device__ __forceinline__ void gstep(const _Float16* __restrict__ A,
                                      const _Float16* __restrict__ pb,
                                      int m0, int nf0, int t, int nkt,
                                      int wid, int lane, int r, int kq,
                                      _Float16 (&As)[3][128][64],
                                      half8 (&bb)[8],
                                      f32x4 (&acc)[8][4]) {
    half8 ra[8];

    // ---- tile top: own vmcnt lands A(t) ; barrier publishes all waves' A(t) ----
    if (t + 1 < nkt) asm volatile("s_waitcnt vmcnt(12)" ::: "memory");
    else             asm volatile("s_waitcnt vmcnt(8)"  ::: "memory");
    __builtin_amdgcn_s_barrier();
    __builtin_amdgcn_sched_barrier(0);       // pin reads below barrier (rule #18)

    // ---- ph0: ds ra (ksub0, 8 rows) ; stage A(t+2) ; MFMA x32 ----
#pragma unroll
    for (int mi = 0; mi < 8; mi++) ra[mi] = frag64(&As[TA][0][0], mi * 16 + r, 0, kq);
    if (t + 2 < nkt) stageA64(A, m0, (t + 2) << 6, &As[(TA + 2) % 3][0][0], wid, lane);
    __builtin_amdgcn_s_setprio(1);
#pragma unroll
    for (int mi = 0; mi < 8; mi++)
#pragma unroll
        for (int ni = 0; ni < 4; ni++)
            acc[mi][ni] = __builtin_amdgcn_mfma_f32_16x16x32_f16(ra[mi], bb[ni], acc[mi][ni], 0, 0, 0);
    __builtin_amdgcn_s_setprio(0);

    // ---- ph1: ds ra (ksub1) ; MFMA x32 ; late bb(t+1) x8 ; end barrier ----
#pragma unroll
    for (int mi = 0; mi < 8; mi++) ra[mi] = frag64(&As[TA][0][0], mi * 16 + r, 1, kq);
    __builtin_amdgcn_s_setprio(1);
#pragma unroll
    for (int mi = 0; mi < 8; mi++)
#pragma unroll
        for (int ni = 0; ni < 4; ni++)
            acc[mi][ni] = __builtin_amdgcn_mfma_f32_16x16x32_f16(ra[mi], bb[4 + ni], acc[mi][ni], 0, 0, 0);
    __builtin_amdgcn_s_setprio(0);
    if (t + 1 < nkt) {
        int k0 = (t + 1) << 1;
        bb[0] = bload(pb, nf0,      k0,     lane);
        bb[1] = bload(pb, nf0 + 1,  k0,     lane);
        bb[2] = bload(pb, nf0 + 64, k0,     lane);
        bb[3] = bload(pb, nf0 + 65, k0,     lane);
        bb[4] = bload(pb, nf0,      k0 + 1, lane);
        bb[5] = bload(pb, nf0 + 1,  k0 + 1, lane);
        bb[6] = bload(pb, nf0 + 64, k0 + 1, lane);
        bb[7] = bload(pb, nf0 + 65, k0 + 1, lane);
    }
    __builtin_amdgcn_s_barrier();            // A reads consumed -> restage safe
}

__global__ __launch_bounds__(256, 2) void gemm256(const _Float16* __restrict__ A,
                                                  const _Float16* __restrict__ pk,
                                                  _Float16* __restrict__ out_u,
                                                  _Float16* __restrict__ out_c,
                                                  float* __restrict__ Ac,
                                                  float* __restrict__ Bc) {
    __shared__ _Float16 As[3][128][64];   // 48 KiB (A only; B bypasses LDS)

    int bid = blockIdx.x;                 // 2048 blocks
    int xcd = bid & 7, lin = bid >> 3;    // 256 blocks/XCD
    int mt = xcd * 32 + (lin >> 3);       // 32 mt x 8 nt per XCD (x panel reused 8x)
    int nt = lin & 7;                     // 128-col pair (gate + comb)
    int m0 = mt * 128;

    int tid = threadIdx.x, wid = tid >> 6, lane = tid & 63;
    int wc = wid;                          // wave owns 32 paired cols
    int r = lane & 15, kq = lane >> 4;
    int nf0 = nt * 8 + wc * 2;             // packed gate-frag base for this wave

    f32x4 acc[8][4];
#pragma unroll
    for (int i = 0; i < 8; i++)
#pragma unroll
        for (int j = 0; j < 4; j++) acc[i][j] = (f32x4)0.f;

    half8 bb[8];
    const int nkt = K_DIM >> 6;            // 16 K-tiles of BK=64

    // ---- prologue: stage A(0),A(1) ; load bb(0) ; loop-top vmcnt handles wait ----
    stageA64(A, m0, 0,  &As[0][0][0], wid, lane);
    stageA64(A, m0, 64, &As[1][0][0], wid, lane);
    bb[0] = bload(pk, nf0,      0, lane);
    bb[1] = bload(pk, nf0 + 1,  0, lane);
    bb[2] = bload(pk, nf0 + 64, 0, lane);
    bb[3] = bload(pk, nf0 + 65, 0, lane);
    bb[4] = bload(pk, nf0,      1, lane);
    bb[5] = bload(pk, nf0 + 1,  1, lane);
    bb[6] = bload(pk, nf0 + 64, 1, lane);
    bb[7] = bload(pk, nf0 + 65, 1, lane);

    for (int t0 = 0; t0 < nkt; t0 += 3) {
        gstep<0>(A, pk, m0, nf0, t0, nkt, wid, lane, r, kq, As, bb, acc);
        if (t0 + 1 < nkt)
            gstep<1>(A, pk, m0, nf0, t0 + 1, nkt, wid, lane, r, kq, As, bb, acc);
        if (t0 + 2 < nkt)
            gstep<2>(A, pk, m0, nf0, t0 + 2, nkt, wid, lane, r, kq, As, bb, acc);
    }

    // ---- epilogue: write u/cand fp16 AND per-16-row affine segments (pass1) ----
    // C/D layout: col = lane&15 (=r), row = kq*4 + q (+ mi*16). t_local = kq*4+q.
    int rr = kq * 4;
#pragma unroll
    for (int mi = 0; mi < 8; mi++) {
        int mbase = m0 + mi * 16 + rr;
        float Aab[2] = {1.f, 1.f}, Bab[2] = {0.f, 0.f};
#pragma unroll
        for (int ni = 0; ni < 2; ni++) {
            int d = nt * 128 + wc * 32 + ni * 16 + r;
#pragma unroll
            for (int q = 0; q < 4; q++) {   // t ascending within lane's 4-run
                float u = 1.f / (1.f + __expf(-acc[mi][ni][q]));
                float c = acc[mi][ni + 2][q];
                size_t m = (size_t)(mbase + q);
                out_u[m * D_DIM + d] = (_Float16)u;
                out_c[m * D_DIM + d] = (_Float16)c;
                Bab[ni] = fmaf(u, Bab[ni], (1.f - u) * c);
                Aab[ni] *= u;
            }
        }
        // ordered butterfly compose across the 4 kq lanes (t-runs kq*4..+4)
#pragma unroll
        for (int ni = 0; ni < 2; ni++) {
            float Aa = Aab[ni], Bb = Bab[ni];
            float oA = __shfl_xor(Aa, 16), oB = __shfl_xor(Bb, 16);
            if (kq & 1) { Bb = fmaf(Aa, oB, Bb); Aa *= oA; }   // mine later
            else        { Bb = fmaf(oA, Bb, oB); Aa *= oA; }   // other later
            oA = __shfl_xor(Aa, 32); oB = __shfl_xor(Bb, 32);
            if (kq & 2) { Bb = fmaf(Aa, oB, Bb); Aa *= oA; }
            else        { Bb = fmaf(oA, Bb, oB); Aa *= oA; }
            if (kq == 0) {
                int d = nt * 128 + wc * 32 + ni * 16 + r;
                int bc = mt * 8 + mi;        // global 16-chunk id = b*NCH + ch
                Ac[(size_t)bc * 1024 + d] = Aa;
                Bc[(size_t)bc * 1024 + d] = Bb;
            }
        }
    }
}

// ========== split-K W_comb GEMM (128x128 tile, r2-validated structure) ==========
__global__ __launch_bounds__(256) void wcomb_splitk(const _Float16* __restrict__ A,
                                                    const _Float16* __restrict__ Bm,
                                                    float* __restrict__ part) {
    __shared__ _Float16 As[128 * 32];
    __shared__ _Float16 Bs[128 * 32];
    int bid = blockIdx.x;                 // mt + 8*nt + 64*slice
    int mt = bid & 7, nt = (bid >> 3) & 7, sl = bid >> 6;
    int m0 = mt * 128, n0 = nt * 128, kbeg = sl * 256;
    int tid = threadIdx.x, wid = tid >> 6, lane = tid & 63;
    int wr = wid >> 1, wc = wid & 1;

    f32x4 acc[4][4];
#pragma unroll
    for (int i = 0; i < 4; i++)
#pragma unroll
        for (int j = 0; j < 4; j++) acc[i][j] = (f32x4)0.f;

    int r = lane & 15, kq = lane >> 4;

    for (int kt = kbeg; kt < kbeg + 256; kt += 32) {
        __syncthreads();
#pragma unroll
        for (int j = 0; j < 2; ++j) {
            int f = j * 256 + tid;
            int row = f >> 2, kc = f & 3;
            gl_lds16(A + (size_t)(m0 + row) * 1024 + kt + kc * 8, As + (size_t)(j * 256 + wid * 64) * 8);
            gl_lds16(Bm + (size_t)(n0 + row) * 1024 + kt + kc * 8, Bs + (size_t)(j * 256 + wid * 64) * 8);
        }
        __syncthreads();
        half8 af[4], bf[4];
#pragma unroll
        for (int mi = 0; mi < 4; mi++) af[mi] = *(const half8*)&As[(wr * 64 + mi * 16 + r) * 32 + kq * 8];
#pragma unroll
        for (int ni = 0; ni < 4; ni++) bf[ni] = *(const half8*)&Bs[(wc * 64 + ni * 16 + r) * 32 + kq * 8];
#pragma unroll
        for (int mi = 0; mi < 4; mi++)
#pragma unroll
            for (int ni = 0; ni < 4; ni++)
                acc[mi][ni] = __builtin_amdgcn_mfma_f32_16x16x32_f16(af[mi], bf[ni], acc[mi][ni], 0, 0, 0);
    }

    int rr = kq * 4;
    float* pbp = part + (size_t)sl * 1048576;
#pragma unroll
    for (int mi = 0; mi < 4; mi++) {
        int mbase = m0 + wr * 64 + mi * 16 + rr;
#pragma unroll
        for (int ni = 0; ni < 4; ni++) {
            int n = n0 + wc * 64 + ni * 16 + r;
#pragma unroll
            for (int q = 0; q < 4; q++)
                pbp[(size_t)(mbase + q) * 1024 + n] = acc[mi][ni][q];
        }
    }
}

// combine 4 split-K slices -> packed comb units (nf 64..127) [r9/r16-validated]
__global__ __launch_bounds__(256) void wcomb_combine_pack(const float* __restrict__ part,
                                                          _Float16* __restrict__ pk) {
    int i = blockIdx.x * 256 + threadIdx.x;   // 0..131071 units
    int ll = i & 63, u = i >> 6;
    int kt = u & 31, nf = u >> 5;             // local nf 0..63
    int e = nf * 16 + (ll & 15);              // W_comb row
    int k = kt * 32 + (ll >> 4) * 8;
    size_t o = (size_t)e * 1024 + k;
    float s[8];
#pragma unroll
    for (int j = 0; j < 8; ++j) s[j] = 0.f;
#pragma unroll
    for (int sl = 0; sl < 4; ++sl) {
        const float4* p = (const float4*)&part[(size_t)sl * 1048576 + o];
        float4 a = p[0], c = p[1];
        s[0] += a.x; s[1] += a.y; s[2] += a.z; s[3] += a.w;
        s[4] += c.x; s[5] += c.y; s[6] += c.z; s[7] += c.w;
    }
    half8 h;
#pragma unroll
    for (int j = 0; j < 8; ++j) h[j] = (_Float16)s[j];
    *(half8*)&pk[1048576 + (size_t)i * 8] = h;   // comb half of packed array
}

// pass 2: sequential over 128 chunks; 64-thread blocks x 256 -> all CUs active.
__global__ __launch_bounds__(64) void scan_pass2(const float* __restrict__ Ac,
                                                 const float* __restrict__ Bc,
                                                 float* __restrict__ h0w) {
    int idx = blockIdx.x * 64 + threadIdx.x;    // b*D + d, 16384 total
    int b = idx >> 10, d = idx & (D_DIM - 1);
    float h = 0.f;
#pragma unroll 8
    for (int ch = 0; ch < NCH; ++ch) {
        size_t k = ((size_t)(b * NCH + ch) << 10) + d;
        float a = Ac[k];
        float bv = Bc[k];
        h0w[k] = h;
        h = fmaf(a, h, bv);
    }
}

// ---- fused scan pass 3 + LayerNorm (1 wave, 16 dims/lane, depth-2 prefetch) ----
__global__ __launch_bounds__(64) void scan_ln(const _Float16* __restrict__ u,
                                              const _Float16* __restrict__ cd,
                                              const float* __restrict__ h0,
                                              const float* __restrict__ gamma,
                                              const float* __restrict__ beta,
                                              float* __restrict__ outp) {
    int bc = blockIdx.x;                // b*NCH + ch
    int b = bc >> 7, ch = bc & (NCH - 1);
    int lane = threadIdx.x;             // 0..63
    int d0 = lane * 16;
    size_t base = ((size_t)b * T_DIM + (size_t)ch * CHUNK) * D_DIM + d0;

    float g[16], be[16], h[16];
#pragma unroll
    for (int j = 0; j < 16; j += 4) {
        *(float4*)&g[j]  = *(const float4*)&gamma[d0 + j];
        *(float4*)&be[j] = *(const float4*)&beta[d0 + j];
    }
    size_t o = (size_t)bc * D_DIM + d0;
#pragma unroll
    for (int j = 0; j < 16; j += 4) *(float4*)&h[j] = *(const float4*)&h0[o + j];

    // depth-2 prefetch: even set (rows 0,2,..) and odd set (rows 1,3,..)
    half8 ua0 = *(const half8*)&u[base];
    half8 ub0 = *(const half8*)&u[base + 8];
    half8 ca0 = *(const half8*)&cd[base];
    half8 cb0 = *(const half8*)&cd[base + 8];
    half8 ua1 = *(const half8*)&u[base + D_DIM];
    half8 ub1 = *(const half8*)&u[base + D_DIM + 8];
    half8 ca1 = *(const half8*)&cd[base + D_DIM];
    half8 cb1 = *(const half8*)&cd[base + D_DIM + 8];

#pragma unroll
    for (int t = 0; t < CHUNK; t += 2) {
        half8 nua0, nub0, nca0, ncb0, nua1, nub1, nca1, ncb1;
        if (t + 2 < CHUNK) {
            size_t nrow = base + (size_t)(t + 2) * D_DIM;
            nua0 = *(const half8*)&u[nrow];
            nub0 = *(const half8*)&u[nrow + 8];
            nca0 = *(const half8*)&cd[nrow];
            ncb0 = *(const half8*)&cd[nrow + 8];
        }
        if (t + 3 < CHUNK) {
            size_t nrow = base + (size_t)(t + 3) * D_DIM;
            nua1 = *(const half8*)&u[nrow];
            nub1 = *(const half8*)&u[nrow + 8];
            nca1 = *(const half8*)&cd[nrow];
            ncb1 = *(const half8*)&cd[nrow + 8];
        }
        // ---- row t (even set) ----
        {
            size_t row = base + (size_t)t * D_DIM;
            float s = 0.f, q = 0.f;
#pragma unroll
            for (int j = 0; j < 8; ++j) {
                float ut = (float)ua0[j], ct = (float)ca0[j];
                h[j] = fmaf(ut, h[j] - ct, ct);
                s += h[j]; q += h[j] * h[j];
            }
#pragma unroll
            for (int j = 0; j < 8; ++j) {
                float ut = (float)ub0[j], ct = (float)cb0[j];
                h[8 + j] = fmaf(ut, h[8 + j] - ct, ct);
                s += h[8 + j]; q += h[8 + j] * h[8 + j];
            }
#pragma unroll
            for (int off = 32; off > 0; off >>= 1) {
                s += __shfl_xor(s, off);
                q += __shfl_xor(q, off);
            }
            float mu = s * (1.f / D_DIM);
            float var = q * (1.f / D_DIM) - mu * mu;
            float rs = rsqrtf(var + LN_EPS);
            float o16[16];
#pragma unroll
            for (int j = 0; j < 16; ++j) o16[j] = (h[j] - mu) * rs * g[j] + be[j];
#pragma unroll
            for (int j = 0; j < 16; j += 4) *(float4*)&outp[row + j] = *(float4*)&o16[j];
        }
        // ---- row t+1 (odd set) ----
        {
            size_t row = base + (size_t)(t + 1) * D_DIM;
            float s = 0.f, q = 0.f;
#pragma unroll
            for (int j = 0; j < 8; ++j) {
                float ut = (float)ua1[j], ct = (float)ca1[j];
                h[j] = fmaf(ut, h[j] - ct, ct);
                s += h[j]; q += h[j] * h[j];
            }
#pragma unroll
            for (int j = 0; j < 8; ++j) {
                float ut = (float)ub1[j], ct = (float)cb1[j];
                h[8 + j] = fmaf(ut, h[8 + j] - ct, ct);
                s += h[8 + j]; q += h[8 + j] * h[8 + j];
            }
#pragma unroll
            for (int off = 32; off > 0; off >>= 1) {
                s += __shfl_xor(s, off);
                q += __shfl_xor(q, off);
            }
            float mu = s * (1.f / D_DIM);
            float var = q * (1.f / D_DIM) - mu * mu;
            float rs = rsqrtf(var + LN_EPS);
            float o16[16];
#pragma unroll
            for (int j = 0; j < 16; ++j) o16[j] = (h[j] - mu) * rs * g[j] + be[j];
#pragma unroll
            for (int j = 0; j < 16; j += 4) *(float4*)&outp[row + j] = *(float4*)&o16[j];
        }
        ua0 = nua0; ub0 = nub0; ca0 = nca0; cb0 = ncb0;
        ua1 = nua1; ub1 = nub1; ca1 = nca1; cb1 = ncb1;
    }
}

extern "C" void kernel_launch(void* const* d_in, const int* in_sizes, int n_in,
                              void* d_out, int out_size, void* d_ws, size_t ws_size,
                              hipStream_t stream) {
    const float* x       = (const float*)d_in[0];
    const float* W_in    = (const float*)d_in[1];
    const float* W_state = (const float*)d_in[2];
    const float* gamma   = (const float*)d_in[3];
    const float* beta    = (const float*)d_in[4];
    float* out = (float*)d_out;

    char* w = (char*)d_ws;
    size_t off = 0;
    auto carve = [&](size_t bytes) {
        void* p = w + off;
        off += (bytes + 255) & ~(size_t)255;
        return p;
    };
    _Float16* xh   = (_Float16*)carve((size_t)M_TOT * K_DIM * 2);           // 64 MiB
    _Float16* pk   = (_Float16*)carve((size_t)2 * D_DIM * K_DIM * 2);       // 4 MiB packed W
    _Float16* uarr = (_Float16*)carve((size_t)M_TOT * D_DIM * 2);           // 64 MiB
    _Float16* cand = (_Float16*)carve((size_t)M_TOT * D_DIM * 2);           // 64 MiB
    char* scratch  = (char*)carve((size_t)16 * 1024 * 1024);                // 16 MiB shared region
    _Float16* wvxT = (_Float16*)scratch;                                    // 2 MiB (early)
    _Float16* wst  = (_Float16*)(scratch + 2 * 1024 * 1024);                // 2 MiB (early)
    float* Ac = (float*)scratch;                                            // 8 MiB (late)
    float* Bc = (float*)(scratch + 8 * 1024 * 1024);                        // 8 MiB (late)
    float* wpart = (float*)cand;   // 16 MiB fp32 partials; cand dead until main GEMM
    float* h0w = (float*)xh;       // 8 MiB; xh dead after gemm256

    // 1. merged prep (x cvt | gate pack | W_state cvt | W_vx transpose)
    prep_all<<<4096, 256, 0, stream>>>(x, W_in, W_state, xh, pk, wvxT, wst);

    // 2. W_comb = W_state @ W_vx -> packed comb units  (split-K x4)
    wcomb_splitk<<<256, 256, 0, stream>>>(wst, wvxT, wpart);
    wcomb_combine_pack<<<512, 256, 0, stream>>>(wpart, pk);

    // 3. fused projection + sigmoid + scan_pass1 (128-row, BK=64, B direct, 2 blk/CU)
    gemm256<<<2048, 256, 0, stream>>>(xh, pk, uarr, cand, Ac, Bc);

    // 4. cross-chunk scan (all-CU spread) + fused pass3/LN (depth-2 prefetch)
    scan_pass2<<<(B_DIM * D_DIM) / 64, 64, 0, stream>>>(Ac, Bc, h0w);
    scan_ln<<<B_DIM * NCH, 64, 0, stream>>>(uarr, cand, h0w, gamma, beta, out);
}

// Round 22
// 266.778 us; speedup vs baseline: 1.1320x; 1.0594x over previous
//
#include <hip/hip_runtime.h>

// ---- problem constants ----
#define D_DIM 1024
#define B_DIM 16
#define T_DIM 2048
#define M_TOT (B_DIM * T_DIM)   // 32768 rows
#define K_DIM 1024
#define LN_EPS 1e-5f
#define CHUNK 16
#define NCH (T_DIM / CHUNK)     // 128 chunks

typedef _Float16 half8 __attribute__((ext_vector_type(8)));
typedef _Float16 half4v __attribute__((ext_vector_type(4)));
typedef float f32x4 __attribute__((ext_vector_type(4)));

// ============ packed-B layout (r9/r16-validated) ============
// 16B unit index = (nf*32 + kt)*64 + lane; n = nf*16 + (lane&15),
// k = kt*32 + (lane>>4)*8. Gate frags nf 0..63; comb frags nf 64..127.

// ------- merged prep: x cvt | gate pack | W_state cvt | W_vx transpose -------
__global__ __launch_bounds__(256) void prep_all(const float* __restrict__ x,
                                                const float* __restrict__ W_in,
                                                const float* __restrict__ W_state,
                                                _Float16* __restrict__ xh,
                                                _Float16* __restrict__ pk,
                                                _Float16* __restrict__ wvxT,
                                                _Float16* __restrict__ wst) {
    __shared__ _Float16 t[32][33];
    int b = blockIdx.x, tid = threadIdx.x;
    if (b < 2048) {                      // x -> fp16, grid-stride (4M half8 units)
        int i = b * 256 + tid;
        for (; i < M_TOT * K_DIM / 8; i += 2048 * 256) {
            const float4* p = (const float4*)x + 2 * (size_t)i;
            float4 a = p[0], c = p[1];
            half8 h;
            h[0] = (_Float16)a.x; h[1] = (_Float16)a.y; h[2] = (_Float16)a.z; h[3] = (_Float16)a.w;
            h[4] = (_Float16)c.x; h[5] = (_Float16)c.y; h[6] = (_Float16)c.z; h[7] = (_Float16)c.w;
            ((half8*)xh)[i] = h;
        }
    } else if (b < 2560) {               // gate W -> packed units 0..131071
        int i = (b - 2048) * 256 + tid;
        int ll = i & 63, u = i >> 6;
        int kt = u & 31, nf = u >> 5;    // nf 0..63
        int n = nf * 16 + (ll & 15);
        int k = kt * 32 + (ll >> 4) * 8;
        const float4* s = (const float4*)&W_in[(size_t)n * 1024 + k];
        float4 a = s[0], c = s[1];
        half8 h;
        h[0] = (_Float16)a.x; h[1] = (_Float16)a.y; h[2] = (_Float16)a.z; h[3] = (_Float16)a.w;
        h[4] = (_Float16)c.x; h[5] = (_Float16)c.y; h[6] = (_Float16)c.z; h[7] = (_Float16)c.w;
        *(half8*)&pk[(size_t)i * 8] = h;
    } else if (b < 3072) {               // W_state -> wst (fp16)
        int i = (b - 2560) * 256 + tid;
        const float4* p = (const float4*)W_state + 2 * (size_t)i;
        float4 a = p[0], c = p[1];
        half8 h;
        h[0] = (_Float16)a.x; h[1] = (_Float16)a.y; h[2] = (_Float16)a.z; h[3] = (_Float16)a.w;
        h[4] = (_Float16)c.x; h[5] = (_Float16)c.y; h[6] = (_Float16)c.z; h[7] = (_Float16)c.w;
        ((half8*)wst)[i] = h;
    } else {                             // W_vx^T -> wvxT (32x32 tiles)
        int tile = b - 3072;             // 0..1023
        int bx = (tile & 31) * 32, by = (tile >> 5) * 32;
        int tx = tid & 31, ty = tid >> 5; // (32,8)
        const float* src = W_in + (size_t)D_DIM * K_DIM;
#pragma unroll
        for (int j = 0; j < 4; ++j)
            t[ty + 8 * j][tx] = (_Float16)src[(size_t)(by + ty + 8 * j) * 1024 + bx + tx];
        __syncthreads();
#pragma unroll
        for (int j = 0; j < 4; ++j)
            wvxT[(size_t)(bx + ty + 8 * j) * 1024 + by + tx] = t[tx][ty + 8 * j];
    }
}

// ---------------- async global->LDS helper ----------------
__device__ __forceinline__ void gl_lds16(const _Float16* g, _Float16* l) {
    __builtin_amdgcn_global_load_lds(
        (const __attribute__((address_space(1))) unsigned int*)g,
        (__attribute__((address_space(3))) unsigned int*)l,
        16, 0, 0);
}

// ====== 128-row x (128 gate + 128 comb) MFMA GEMM, BK=64, 2 blocks/CU (r21) ======
// Stage 128x64 A-tile (16 KiB, 1024 chunks) = 4 gl_lds / thread.
__device__ __forceinline__ void stageA64(const _Float16* __restrict__ G,
                                         int row0, int kt,
                                         _Float16* lds0, int wid, int lane) {
#pragma unroll
    for (int call = 0; call < 4; ++call) {
        int c0 = call * 256 + wid * 64;
        int c  = c0 + lane;                 // chunk 0..1023
        int rl = c >> 3;                    // row 0..127 (8 chunks/row)
        int cc = c & 7;
        int src = cc ^ (rl & 7);            // both-sides swizzle
        gl_lds16(G + (size_t)(row0 + rl) * 1024 + kt + src * 8,
                 lds0 + (size_t)c0 * 8);
    }
}

// Fragment read: logical chunk lc = ksub*4 + kq, physical = lc ^ (row&7).
__device__ __forceinline__ half8 frag64(const _Float16* base, int row, int ksub, int kq) {
    int pc = ((ksub << 2) | kq) ^ (row & 7);
    return *(const half8*)(base + (size_t)row * 64 + pc * 8);
}

// B-frag: one coalesced 16B load per lane from packed layout (L2-resident)
__device__ __forceinline__ half8 bload(const _Float16* __restrict__ pb,
                                       int nf, int kt, int lane) {
    return *(const half8*)(pb + (((size_t)nf * 32 + kt) * 64 + lane) * 8);
}

template <int TA>
__device__ __forceinline__ void gstep(const _Float16* __restrict__ A,
                                      const _Float16* __restrict__ pb,
                                      int m0, int nf0, int t, int nkt,
                                      int wid, int lane, int r, int kq,
                                      _Float16 (&As)[3][128][64],
                                      half8 (&bb)[8],
                                      f32x4 (&acc)[8][4]) {
    half8 ra[8];

    // ---- tile top: own vmcnt lands A(t) ; barrier publishes all waves' A(t) ----
    if (t + 1 < nkt) asm volatile("s_waitcnt vmcnt(12)" ::: "memory");
    else             asm volatile("s_waitcnt vmcnt(8)"  ::: "memory");
    __builtin_amdgcn_s_barrier();
    __builtin_amdgcn_sched_barrier(0);       // pin reads below barrier (rule #18)

    // ---- ph0: ds ra (ksub0, 8 rows) ; stage A(t+2) ; MFMA x32 ----
#pragma unroll
    for (int mi = 0; mi < 8; mi++) ra[mi] = frag64(&As[TA][0][0], mi * 16 + r, 0, kq);
    if (t + 2 < nkt) stageA64(A, m0, (t + 2) << 6, &As[(TA + 2) % 3][0][0], wid, lane);
    __builtin_amdgcn_s_setprio(1);
#pragma unroll
    for (int mi = 0; mi < 8; mi++)
#pragma unroll
        for (int ni = 0; ni < 4; ni++)
            acc[mi][ni] = __builtin_amdgcn_mfma_f32_16x16x32_f16(ra[mi], bb[ni], acc[mi][ni], 0, 0, 0);
    __builtin_amdgcn_s_setprio(0);

    // ---- ph1: ds ra (ksub1) ; MFMA x32 ; late bb(t+1) x8 ; end barrier ----
#pragma unroll
    for (int mi = 0; mi < 8; mi++) ra[mi] = frag64(&As[TA][0][0], mi * 16 + r, 1, kq);
    __builtin_amdgcn_s_setprio(1);
#pragma unroll
    for (int mi = 0; mi < 8; mi++)
#pragma unroll
        for (int ni = 0; ni < 4; ni++)
            acc[mi][ni] = __builtin_amdgcn_mfma_f32_16x16x32_f16(ra[mi], bb[4 + ni], acc[mi][ni], 0, 0, 0);
    __builtin_amdgcn_s_setprio(0);
    if (t + 1 < nkt) {
        int k0 = (t + 1) << 1;
        bb[0] = bload(pb, nf0,      k0,     lane);
        bb[1] = bload(pb, nf0 + 1,  k0,     lane);
        bb[2] = bload(pb, nf0 + 64, k0,     lane);
        bb[3] = bload(pb, nf0 + 65, k0,     lane);
        bb[4] = bload(pb, nf0,      k0 + 1, lane);
        bb[5] = bload(pb, nf0 + 1,  k0 + 1, lane);
        bb[6] = bload(pb, nf0 + 64, k0 + 1, lane);
        bb[7] = bload(pb, nf0 + 65, k0 + 1, lane);
    }
    __builtin_amdgcn_s_barrier();            // A reads consumed -> restage safe
}

__global__ __launch_bounds__(256, 2) void gemm256(const _Float16* __restrict__ A,
                                                  const _Float16* __restrict__ pk,
                                                  _Float16* __restrict__ out_u,
                                                  _Float16* __restrict__ out_c,
                                                  float* __restrict__ Ac,
                                                  float* __restrict__ Bc) {
    __shared__ _Float16 As[3][128][64];   // 48 KiB (A only; B bypasses LDS)

    int bid = blockIdx.x;                 // 2048 blocks
    int xcd = bid & 7, lin = bid >> 3;    // 256 blocks/XCD
    int mt = xcd * 32 + (lin >> 3);       // 32 mt x 8 nt per XCD (x panel reused 8x)
    int nt = lin & 7;                     // 128-col pair (gate + comb)
    int m0 = mt * 128;

    int tid = threadIdx.x, wid = tid >> 6, lane = tid & 63;
    int wc = wid;                          // wave owns 32 paired cols
    int r = lane & 15, kq = lane >> 4;
    int nf0 = nt * 8 + wc * 2;             // packed gate-frag base for this wave

    f32x4 acc[8][4];
#pragma unroll
    for (int i = 0; i < 8; i++)
#pragma unroll
        for (int j = 0; j < 4; j++) acc[i][j] = (f32x4)0.f;

    half8 bb[8];
    const int nkt = K_DIM >> 6;            // 16 K-tiles of BK=64

    // ---- prologue: stage A(0),A(1) ; load bb(0) ; loop-top vmcnt handles wait ----
    stageA64(A, m0, 0,  &As[0][0][0], wid, lane);
    stageA64(A, m0, 64, &As[1][0][0], wid, lane);
    bb[0] = bload(pk, nf0,      0, lane);
    bb[1] = bload(pk, nf0 + 1,  0, lane);
    bb[2] = bload(pk, nf0 + 64, 0, lane);
    bb[3] = bload(pk, nf0 + 65, 0, lane);
    bb[4] = bload(pk, nf0,      1, lane);
    bb[5] = bload(pk, nf0 + 1,  1, lane);
    bb[6] = bload(pk, nf0 + 64, 1, lane);
    bb[7] = bload(pk, nf0 + 65, 1, lane);

    for (int t0 = 0; t0 < nkt; t0 += 3) {
        gstep<0>(A, pk, m0, nf0, t0, nkt, wid, lane, r, kq, As, bb, acc);
        if (t0 + 1 < nkt)
            gstep<1>(A, pk, m0, nf0, t0 + 1, nkt, wid, lane, r, kq, As, bb, acc);
        if (t0 + 2 < nkt)
            gstep<2>(A, pk, m0, nf0, t0 + 2, nkt, wid, lane, r, kq, As, bb, acc);
    }

    // ---- epilogue: write u/cand fp16 AND per-16-row affine segments (pass1) ----
    // C/D layout: col = lane&15 (=r), row = kq*4 + q (+ mi*16). t_local = kq*4+q.
    int rr = kq * 4;
#pragma unroll
    for (int mi = 0; mi < 8; mi++) {
        int mbase = m0 + mi * 16 + rr;
        float Aab[2] = {1.f, 1.f}, Bab[2] = {0.f, 0.f};
#pragma unroll
        for (int ni = 0; ni < 2; ni++) {
            int d = nt * 128 + wc * 32 + ni * 16 + r;
#pragma unroll
            for (int q = 0; q < 4; q++) {   // t ascending within lane's 4-run
                float u = 1.f / (1.f + __expf(-acc[mi][ni][q]));
                float c = acc[mi][ni + 2][q];
                size_t m = (size_t)(mbase + q);
                out_u[m * D_DIM + d] = (_Float16)u;
                out_c[m * D_DIM + d] = (_Float16)c;
                Bab[ni] = fmaf(u, Bab[ni], (1.f - u) * c);
                Aab[ni] *= u;
            }
        }
        // ordered butterfly compose across the 4 kq lanes (t-runs kq*4..+4)
#pragma unroll
        for (int ni = 0; ni < 2; ni++) {
            float Aa = Aab[ni], Bb = Bab[ni];
            float oA = __shfl_xor(Aa, 16), oB = __shfl_xor(Bb, 16);
            if (kq & 1) { Bb = fmaf(Aa, oB, Bb); Aa *= oA; }   // mine later
            else        { Bb = fmaf(oA, Bb, oB); Aa *= oA; }   // other later
            oA = __shfl_xor(Aa, 32); oB = __shfl_xor(Bb, 32);
            if (kq & 2) { Bb = fmaf(Aa, oB, Bb); Aa *= oA; }
            else        { Bb = fmaf(oA, Bb, oB); Aa *= oA; }
            if (kq == 0) {
                int d = nt * 128 + wc * 32 + ni * 16 + r;
                int bc = mt * 8 + mi;        // global 16-chunk id = b*NCH + ch
                Ac[(size_t)bc * 1024 + d] = Aa;
                Bc[(size_t)bc * 1024 + d] = Bb;
            }
        }
    }
}

// ========== split-K W_comb GEMM (128x128 tile, r2-validated structure) ==========
__global__ __launch_bounds__(256) void wcomb_splitk(const _Float16* __restrict__ A,
                                                    const _Float16* __restrict__ Bm,
                                                    float* __restrict__ part) {
    __shared__ _Float16 As[128 * 32];
    __shared__ _Float16 Bs[128 * 32];
    int bid = blockIdx.x;                 // mt + 8*nt + 64*slice
    int mt = bid & 7, nt = (bid >> 3) & 7, sl = bid >> 6;
    int m0 = mt * 128, n0 = nt * 128, kbeg = sl * 256;
    int tid = threadIdx.x, wid = tid >> 6, lane = tid & 63;
    int wr = wid >> 1, wc = wid & 1;

    f32x4 acc[4][4];
#pragma unroll
    for (int i = 0; i < 4; i++)
#pragma unroll
        for (int j = 0; j < 4; j++) acc[i][j] = (f32x4)0.f;

    int r = lane & 15, kq = lane >> 4;

    for (int kt = kbeg; kt < kbeg + 256; kt += 32) {
        __syncthreads();
#pragma unroll
        for (int j = 0; j < 2; ++j) {
            int f = j * 256 + tid;
            int row = f >> 2, kc = f & 3;
            gl_lds16(A + (size_t)(m0 + row) * 1024 + kt + kc * 8, As + (size_t)(j * 256 + wid * 64) * 8);
            gl_lds16(Bm + (size_t)(n0 + row) * 1024 + kt + kc * 8, Bs + (size_t)(j * 256 + wid * 64) * 8);
        }
        __syncthreads();
        half8 af[4], bf[4];
#pragma unroll
        for (int mi = 0; mi < 4; mi++) af[mi] = *(const half8*)&As[(wr * 64 + mi * 16 + r) * 32 + kq * 8];
#pragma unroll
        for (int ni = 0; ni < 4; ni++) bf[ni] = *(const half8*)&Bs[(wc * 64 + ni * 16 + r) * 32 + kq * 8];
#pragma unroll
        for (int mi = 0; mi < 4; mi++)
#pragma unroll
            for (int ni = 0; ni < 4; ni++)
                acc[mi][ni] = __builtin_amdgcn_mfma_f32_16x16x32_f16(af[mi], bf[ni], acc[mi][ni], 0, 0, 0);
    }

    int rr = kq * 4;
    float* pbp = part + (size_t)sl * 1048576;
#pragma unroll
    for (int mi = 0; mi < 4; mi++) {
        int mbase = m0 + wr * 64 + mi * 16 + rr;
#pragma unroll
        for (int ni = 0; ni < 4; ni++) {
            int n = n0 + wc * 64 + ni * 16 + r;
#pragma unroll
            for (int q = 0; q < 4; q++)
                pbp[(size_t)(mbase + q) * 1024 + n] = acc[mi][ni][q];
        }
    }
}

// combine 4 split-K slices -> packed comb units (nf 64..127) [r9/r16-validated]
__global__ __launch_bounds__(256) void wcomb_combine_pack(const float* __restrict__ part,
                                                          _Float16* __restrict__ pk) {
    int i = blockIdx.x * 256 + threadIdx.x;   // 0..131071 units
    int ll = i & 63, u = i >> 6;
    int kt = u & 31, nf = u >> 5;             // local nf 0..63
    int e = nf * 16 + (ll & 15);              // W_comb row
    int k = kt * 32 + (ll >> 4) * 8;
    size_t o = (size_t)e * 1024 + k;
    float s[8];
#pragma unroll
    for (int j = 0; j < 8; ++j) s[j] = 0.f;
#pragma unroll
    for (int sl = 0; sl < 4; ++sl) {
        const float4* p = (const float4*)&part[(size_t)sl * 1048576 + o];
        float4 a = p[0], c = p[1];
        s[0] += a.x; s[1] += a.y; s[2] += a.z; s[3] += a.w;
        s[4] += c.x; s[5] += c.y; s[6] += c.z; s[7] += c.w;
    }
    half8 h;
#pragma unroll
    for (int j = 0; j < 8; ++j) h[j] = (_Float16)s[j];
    *(half8*)&pk[1048576 + (size_t)i * 8] = h;   // comb half of packed array
}

// pass 2: sequential over 128 chunks; 64-thread blocks x 256 -> all CUs active.
__global__ __launch_bounds__(64) void scan_pass2(const float* __restrict__ Ac,
                                                 const float* __restrict__ Bc,
                                                 float* __restrict__ h0w) {
    int idx = blockIdx.x * 64 + threadIdx.x;    // b*D + d, 16384 total
    int b = idx >> 10, d = idx & (D_DIM - 1);
    float h = 0.f;
#pragma unroll 8
    for (int ch = 0; ch < NCH; ++ch) {
        size_t k = ((size_t)(b * NCH + ch) << 10) + d;
        float a = Ac[k];
        float bv = Bc[k];
        h0w[k] = h;
        h = fmaf(a, h, bv);
    }
}

// ---- fused scan pass 3 + LayerNorm: 2 waves/chunk (512 dims each, 8/lane),
// ---- depth-2 prefetch, parity-double-buffered cross-wave LN reduce ----
__global__ __launch_bounds__(128) void scan_ln(const _Float16* __restrict__ u,
                                               const _Float16* __restrict__ cd,
                                               const float* __restrict__ h0,
                                               const float* __restrict__ gamma,
                                               const float* __restrict__ beta,
                                               float* __restrict__ outp) {
    int bc = blockIdx.x;                // b*NCH + ch
    int b = bc >> 7, ch = bc & (NCH - 1);
    int tid = threadIdx.x;
    int wv = tid >> 6, lane = tid & 63; // 2 waves
    int d0 = wv * 512 + lane * 8;       // 8 dims/lane
    size_t base = ((size_t)b * T_DIM + (size_t)ch * CHUNK) * D_DIM + d0;

    __shared__ float ls[2][2], lq[2][2];   // [parity][wave]

    float g[8], be[8], h[8];
    *(float4*)&g[0]  = *(const float4*)&gamma[d0];
    *(float4*)&g[4]  = *(const float4*)&gamma[d0 + 4];
    *(float4*)&be[0] = *(const float4*)&beta[d0];
    *(float4*)&be[4] = *(const float4*)&beta[d0 + 4];
    size_t o = (size_t)bc * D_DIM + d0;
    *(float4*)&h[0] = *(const float4*)&h0[o];
    *(float4*)&h[4] = *(const float4*)&h0[o + 4];

    // depth-2 prefetch (one u/cand half8 pair per row per lane)
    half8 ua0 = *(const half8*)&u[base];
    half8 ca0 = *(const half8*)&cd[base];
    half8 ua1 = *(const half8*)&u[base + D_DIM];
    half8 ca1 = *(const half8*)&cd[base + D_DIM];

#pragma unroll
    for (int t = 0; t < CHUNK; t += 2) {
        half8 nua0, nca0, nua1, nca1;
        if (t + 2 < CHUNK) {
            size_t nrow = base + (size_t)(t + 2) * D_DIM;
            nua0 = *(const half8*)&u[nrow];
            nca0 = *(const half8*)&cd[nrow];
        }
        if (t + 3 < CHUNK) {
            size_t nrow = base + (size_t)(t + 3) * D_DIM;
            nua1 = *(const half8*)&u[nrow];
            nca1 = *(const half8*)&cd[nrow];
        }
        // ---- row t (even; parity slot 0) ----
        {
            size_t row = base + (size_t)t * D_DIM;
            float s = 0.f, q = 0.f;
#pragma unroll
            for (int j = 0; j < 8; ++j) {
                float ut = (float)ua0[j], ct = (float)ca0[j];
                h[j] = fmaf(ut, h[j] - ct, ct);
                s += h[j]; q += h[j] * h[j];
            }
#pragma unroll
            for (int off = 32; off > 0; off >>= 1) {
                s += __shfl_xor(s, off);
                q += __shfl_xor(q, off);
            }
            if (lane == 0) { ls[0][wv] = s; lq[0][wv] = q; }
            __syncthreads();
            s = ls[0][0] + ls[0][1];
            q = lq[0][0] + lq[0][1];
            float mu = s * (1.f / D_DIM);
            float var = q * (1.f / D_DIM) - mu * mu;
            float rs = rsqrtf(var + LN_EPS);
            float o8[8];
#pragma unroll
            for (int j = 0; j < 8; ++j) o8[j] = (h[j] - mu) * rs * g[j] + be[j];
            *(float4*)&outp[row]     = *(float4*)&o8[0];
            *(float4*)&outp[row + 4] = *(float4*)&o8[4];
        }
        // ---- row t+1 (odd; parity slot 1) ----
        {
            size_t row = base + (size_t)(t + 1) * D_DIM;
            float s = 0.f, q = 0.f;
#pragma unroll
            for (int j = 0; j < 8; ++j) {
                float ut = (float)ua1[j], ct = (float)ca1[j];
                h[j] = fmaf(ut, h[j] - ct, ct);
                s += h[j]; q += h[j] * h[j];
            }
#pragma unroll
            for (int off = 32; off > 0; off >>= 1) {
                s += __shfl_xor(s, off);
                q += __shfl_xor(q, off);
            }
            if (lane == 0) { ls[1][wv] = s; lq[1][wv] = q; }
            __syncthreads();
            s = ls[1][0] + ls[1][1];
            q = lq[1][0] + lq[1][1];
            float mu = s * (1.f / D_DIM);
            float var = q * (1.f / D_DIM) - mu * mu;
            float rs = rsqrtf(var + LN_EPS);
            float o8[8];
#pragma unroll
            for (int j = 0; j < 8; ++j) o8[j] = (h[j] - mu) * rs * g[j] + be[j];
            *(float4*)&outp[row]     = *(float4*)&o8[0];
            *(float4*)&outp[row + 4] = *(float4*)&o8[4];
        }
        ua0 = nua0; ca0 = nca0;
        ua1 = nua1; ca1 = nca1;
    }
}

extern "C" void kernel_launch(void* const* d_in, const int* in_sizes, int n_in,
                              void* d_out, int out_size, void* d_ws, size_t ws_size,
                              hipStream_t stream) {
    const float* x       = (const float*)d_in[0];
    const float* W_in    = (const float*)d_in[1];
    const float* W_state = (const float*)d_in[2];
    const float* gamma   = (const float*)d_in[3];
    const float* beta    = (const float*)d_in[4];
    float* out = (float*)d_out;

    char* w = (char*)d_ws;
    size_t off = 0;
    auto carve = [&](size_t bytes) {
        void* p = w + off;
        off += (bytes + 255) & ~(size_t)255;
        return p;
    };
    _Float16* xh   = (_Float16*)carve((size_t)M_TOT * K_DIM * 2);           // 64 MiB
    _Float16* pk   = (_Float16*)carve((size_t)2 * D_DIM * K_DIM * 2);       // 4 MiB packed W
    _Float16* uarr = (_Float16*)carve((size_t)M_TOT * D_DIM * 2);           // 64 MiB
    _Float16* cand = (_Float16*)carve((size_t)M_TOT * D_DIM * 2);           // 64 MiB
    char* scratch  = (char*)carve((size_t)16 * 1024 * 1024);                // 16 MiB shared region
    _Float16* wvxT = (_Float16*)scratch;                                    // 2 MiB (early)
    _Float16* wst  = (_Float16*)(scratch + 2 * 1024 * 1024);                // 2 MiB (early)
    float* Ac = (float*)scratch;                                            // 8 MiB (late)
    float* Bc = (float*)(scratch + 8 * 1024 * 1024);                        // 8 MiB (late)
    float* wpart = (float*)cand;   // 16 MiB fp32 partials; cand dead until main GEMM
    float* h0w = (float*)xh;       // 8 MiB; xh dead after gemm256

    // 1. merged prep (x cvt | gate pack | W_state cvt | W_vx transpose)
    prep_all<<<4096, 256, 0, stream>>>(x, W_in, W_state, xh, pk, wvxT, wst);

    // 2. W_comb = W_state @ W_vx -> packed comb units  (split-K x4)
    wcomb_splitk<<<256, 256, 0, stream>>>(wst, wvxT, wpart);
    wcomb_combine_pack<<<512, 256, 0, stream>>>(wpart, pk);

    // 3. fused projection + sigmoid + scan_pass1 (128-row, BK=64, B direct, 2 blk/CU)
    gemm256<<<2048, 256, 0, stream>>>(xh, pk, uarr, cand, Ac, Bc);

    // 4. cross-chunk scan (all-CU spread) + fused pass3/LN (2 waves/chunk)
    scan_pass2<<<(B_DIM * D_DIM) / 64, 64, 0, stream>>>(Ac, Bc, h0w);
    scan_ln<<<B_DIM * NCH, 128, 0, stream>>>(uarr, cand, h0w, gamma, beta, out);
}

// Round 23
// 257.472 us; speedup vs baseline: 1.1729x; 1.0361x over previous
//
#include <hip/hip_runtime.h>

// ---- problem constants ----
#define D_DIM 1024
#define B_DIM 16
#define T_DIM 2048
#define M_TOT (B_DIM * T_DIM)   // 32768 rows
#define K_DIM 1024
#define LN_EPS 1e-5f
#define CHUNK 16
#define NCH (T_DIM / CHUNK)     // 128 chunks

typedef _Float16 half8 __attribute__((ext_vector_type(8)));
typedef _Float16 half4v __attribute__((ext_vector_type(4)));
typedef float f32x4 __attribute__((ext_vector_type(4)));

// ============ packed-B layout (r9/r16-validated) ============
// 16B unit index = (nf*32 + kt)*64 + lane; n = nf*16 + (lane&15),
// k = kt*32 + (lane>>4)*8. Gate frags nf 0..63; comb frags nf 64..127.

// ------- merged prep: x cvt | gate pack | W_state cvt | W_vx transpose -------
__global__ __launch_bounds__(256) void prep_all(const float* __restrict__ x,
                                                const float* __restrict__ W_in,
                                                const float* __restrict__ W_state,
                                                _Float16* __restrict__ xh,
                                                _Float16* __restrict__ pk,
                                                _Float16* __restrict__ wvxT,
                                                _Float16* __restrict__ wst) {
    __shared__ _Float16 t[32][33];
    int b = blockIdx.x, tid = threadIdx.x;
    if (b < 2048) {                      // x -> fp16, grid-stride (4M half8 units)
        int i = b * 256 + tid;
        for (; i < M_TOT * K_DIM / 8; i += 2048 * 256) {
            const float4* p = (const float4*)x + 2 * (size_t)i;
            float4 a = p[0], c = p[1];
            half8 h;
            h[0] = (_Float16)a.x; h[1] = (_Float16)a.y; h[2] = (_Float16)a.z; h[3] = (_Float16)a.w;
            h[4] = (_Float16)c.x; h[5] = (_Float16)c.y; h[6] = (_Float16)c.z; h[7] = (_Float16)c.w;
            ((half8*)xh)[i] = h;
        }
    } else if (b < 2560) {               // gate W -> packed units 0..131071
        int i = (b - 2048) * 256 + tid;
        int ll = i & 63, u = i >> 6;
        int kt = u & 31, nf = u >> 5;    // nf 0..63
        int n = nf * 16 + (ll & 15);
        int k = kt * 32 + (ll >> 4) * 8;
        const float4* s = (const float4*)&W_in[(size_t)n * 1024 + k];
        float4 a = s[0], c = s[1];
        half8 h;
        h[0] = (_Float16)a.x; h[1] = (_Float16)a.y; h[2] = (_Float16)a.z; h[3] = (_Float16)a.w;
        h[4] = (_Float16)c.x; h[5] = (_Float16)c.y; h[6] = (_Float16)c.z; h[7] = (_Float16)c.w;
        *(half8*)&pk[(size_t)i * 8] = h;
    } else if (b < 3072) {               // W_state -> wst (fp16)
        int i = (b - 2560) * 256 + tid;
        const float4* p = (const float4*)W_state + 2 * (size_t)i;
        float4 a = p[0], c = p[1];
        half8 h;
        h[0] = (_Float16)a.x; h[1] = (_Float16)a.y; h[2] = (_Float16)a.z; h[3] = (_Float16)a.w;
        h[4] = (_Float16)c.x; h[5] = (_Float16)c.y; h[6] = (_Float16)c.z; h[7] = (_Float16)c.w;
        ((half8*)wst)[i] = h;
    } else {                             // W_vx^T -> wvxT (32x32 tiles)
        int tile = b - 3072;             // 0..1023
        int bx = (tile & 31) * 32, by = (tile >> 5) * 32;
        int tx = tid & 31, ty = tid >> 5; // (32,8)
        const float* src = W_in + (size_t)D_DIM * K_DIM;
#pragma unroll
        for (int j = 0; j < 4; ++j)
            t[ty + 8 * j][tx] = (_Float16)src[(size_t)(by + ty + 8 * j) * 1024 + bx + tx];
        __syncthreads();
#pragma unroll
        for (int j = 0; j < 4; ++j)
            wvxT[(size_t)(bx + ty + 8 * j) * 1024 + by + tx] = t[tx][ty + 8 * j];
    }
}

// ---------------- async global->LDS helper ----------------
__device__ __forceinline__ void gl_lds16(const _Float16* g, _Float16* l) {
    __builtin_amdgcn_global_load_lds(
        (const __attribute__((address_space(1))) unsigned int*)g,
        (__attribute__((address_space(3))) unsigned int*)l,
        16, 0, 0);
}

// ====== 128-row x (128 gate + 128 comb) MFMA GEMM, BK=64, 2 blocks/CU (r21) ======
// Stage 128x64 A-tile (16 KiB, 1024 chunks) = 4 gl_lds / thread.
__device__ __forceinline__ void stageA64(const _Float16* __restrict__ G,
                                         int row0, int kt,
                                         _Float16* lds0, int wid, int lane) {
#pragma unroll
    for (int call = 0; call < 4; ++call) {
        int c0 = call * 256 + wid * 64;
        int c  = c0 + lane;                 // chunk 0..1023
        int rl = c >> 3;                    // row 0..127 (8 chunks/row)
        int cc = c & 7;
        int src = cc ^ (rl & 7);            // both-sides swizzle
        gl_lds16(G + (size_t)(row0 + rl) * 1024 + kt + src * 8,
                 lds0 + (size_t)c0 * 8);
    }
}

// Fragment read: logical chunk lc = ksub*4 + kq, physical = lc ^ (row&7).
__device__ __forceinline__ half8 frag64(const _Float16* base, int row, int ksub, int kq) {
    int pc = ((ksub << 2) | kq) ^ (row & 7);
    return *(const half8*)(base + (size_t)row * 64 + pc * 8);
}

// B-frag: one coalesced 16B load per lane from packed layout (L2-resident)
__device__ __forceinline__ half8 bload(const _Float16* __restrict__ pb,
                                       int nf, int kt, int lane) {
    return *(const half8*)(pb + (((size_t)nf * 32 + kt) * 64 + lane) * 8);
}

template <int TA>
__device__ __forceinline__ void gstep(const _Float16* __restrict__ A,
                                      const _Float16* __restrict__ pb,
                                      int m0, int nf0, int t, int nkt,
                                      int wid, int lane, int r, int kq,
                                      _Float16 (&As)[3][128][64],
                                      half8 (&bb)[8],
                                      f32x4 (&acc)[8][4]) {
    half8 ra[8];

    // ---- tile top: own vmcnt lands A(t) ; barrier publishes all waves' A(t) ----
    if (t + 1 < nkt) asm volatile("s_waitcnt vmcnt(12)" ::: "memory");
    else             asm volatile("s_waitcnt vmcnt(8)"  ::: "memory");
    __builtin_amdgcn_s_barrier();
    __builtin_amdgcn_sched_barrier(0);       // pin reads below barrier (rule #18)

    // ---- ph0: ds ra (ksub0, 8 rows) ; stage A(t+2) ; MFMA x32 ----
#pragma unroll
    for (int mi = 0; mi < 8; mi++) ra[mi] = frag64(&As[TA][0][0], mi * 16 + r, 0, kq);
    if (t + 2 < nkt) stageA64(A, m0, (t + 2) << 6, &As[(TA + 2) % 3][0][0], wid, lane);
    __builtin_amdgcn_s_setprio(1);
#pragma unroll
    for (int mi = 0; mi < 8; mi++)
#pragma unroll
        for (int ni = 0; ni < 4; ni++)
            acc[mi][ni] = __builtin_amdgcn_mfma_f32_16x16x32_f16(ra[mi], bb[ni], acc[mi][ni], 0, 0, 0);
    __builtin_amdgcn_s_setprio(0);

    // ---- ph1: ds ra (ksub1) ; MFMA x32 ; late bb(t+1) x8 ; end barrier ----
#pragma unroll
    for (int mi = 0; mi < 8; mi++) ra[mi] = frag64(&As[TA][0][0], mi * 16 + r, 1, kq);
    __builtin_amdgcn_s_setprio(1);
#pragma unroll
    for (int mi = 0; mi < 8; mi++)
#pragma unroll
        for (int ni = 0; ni < 4; ni++)
            acc[mi][ni] = __builtin_amdgcn_mfma_f32_16x16x32_f16(ra[mi], bb[4 + ni], acc[mi][ni], 0, 0, 0);
    __builtin_amdgcn_s_setprio(0);
    if (t + 1 < nkt) {
        int k0 = (t + 1) << 1;
        bb[0] = bload(pb, nf0,      k0,     lane);
        bb[1] = bload(pb, nf0 + 1,  k0,     lane);
        bb[2] = bload(pb, nf0 + 64, k0,     lane);
        bb[3] = bload(pb, nf0 + 65, k0,     lane);
        bb[4] = bload(pb, nf0,      k0 + 1, lane);
        bb[5] = bload(pb, nf0 + 1,  k0 + 1, lane);
        bb[6] = bload(pb, nf0 + 64, k0 + 1, lane);
        bb[7] = bload(pb, nf0 + 65, k0 + 1, lane);
    }
    __builtin_amdgcn_s_barrier();            // A reads consumed -> restage safe
}

__global__ __launch_bounds__(256, 2) void gemm256(const _Float16* __restrict__ A,
                                                  const _Float16* __restrict__ pk,
                                                  _Float16* __restrict__ out_u,
                                                  _Float16* __restrict__ out_c,
                                                  float* __restrict__ Ac,
                                                  float* __restrict__ Bc) {
    __shared__ _Float16 As[3][128][64];   // 48 KiB (A only; B bypasses LDS)

    int bid = blockIdx.x;                 // 2048 blocks
    int xcd = bid & 7, lin = bid >> 3;    // 256 blocks/XCD
    int mt = xcd * 32 + (lin >> 3);       // 32 mt x 8 nt per XCD (x panel reused 8x)
    int nt = lin & 7;                     // 128-col pair (gate + comb)
    int m0 = mt * 128;

    int tid = threadIdx.x, wid = tid >> 6, lane = tid & 63;
    int wc = wid;                          // wave owns 32 paired cols
    int r = lane & 15, kq = lane >> 4;
    int nf0 = nt * 8 + wc * 2;             // packed gate-frag base for this wave

    f32x4 acc[8][4];
#pragma unroll
    for (int i = 0; i < 8; i++)
#pragma unroll
        for (int j = 0; j < 4; j++) acc[i][j] = (f32x4)0.f;

    half8 bb[8];
    const int nkt = K_DIM >> 6;            // 16 K-tiles of BK=64

    // ---- prologue: stage A(0),A(1) ; load bb(0) ; loop-top vmcnt handles wait ----
    stageA64(A, m0, 0,  &As[0][0][0], wid, lane);
    stageA64(A, m0, 64, &As[1][0][0], wid, lane);
    bb[0] = bload(pk, nf0,      0, lane);
    bb[1] = bload(pk, nf0 + 1,  0, lane);
    bb[2] = bload(pk, nf0 + 64, 0, lane);
    bb[3] = bload(pk, nf0 + 65, 0, lane);
    bb[4] = bload(pk, nf0,      1, lane);
    bb[5] = bload(pk, nf0 + 1,  1, lane);
    bb[6] = bload(pk, nf0 + 64, 1, lane);
    bb[7] = bload(pk, nf0 + 65, 1, lane);

    for (int t0 = 0; t0 < nkt; t0 += 3) {
        gstep<0>(A, pk, m0, nf0, t0, nkt, wid, lane, r, kq, As, bb, acc);
        if (t0 + 1 < nkt)
            gstep<1>(A, pk, m0, nf0, t0 + 1, nkt, wid, lane, r, kq, As, bb, acc);
        if (t0 + 2 < nkt)
            gstep<2>(A, pk, m0, nf0, t0 + 2, nkt, wid, lane, r, kq, As, bb, acc);
    }

    // ---- epilogue: write u/cand fp16 AND per-16-row affine segments (pass1) ----
    // C/D layout: col = lane&15 (=r), row = kq*4 + q (+ mi*16). t_local = kq*4+q.
    int rr = kq * 4;
#pragma unroll
    for (int mi = 0; mi < 8; mi++) {
        int mbase = m0 + mi * 16 + rr;
        float Aab[2] = {1.f, 1.f}, Bab[2] = {0.f, 0.f};
#pragma unroll
        for (int ni = 0; ni < 2; ni++) {
            int d = nt * 128 + wc * 32 + ni * 16 + r;
#pragma unroll
            for (int q = 0; q < 4; q++) {   // t ascending within lane's 4-run
                float u = 1.f / (1.f + __expf(-acc[mi][ni][q]));
                float c = acc[mi][ni + 2][q];
                size_t m = (size_t)(mbase + q);
                out_u[m * D_DIM + d] = (_Float16)u;
                out_c[m * D_DIM + d] = (_Float16)c;
                Bab[ni] = fmaf(u, Bab[ni], (1.f - u) * c);
                Aab[ni] *= u;
            }
        }
        // ordered butterfly compose across the 4 kq lanes (t-runs kq*4..+4)
#pragma unroll
        for (int ni = 0; ni < 2; ni++) {
            float Aa = Aab[ni], Bb = Bab[ni];
            float oA = __shfl_xor(Aa, 16), oB = __shfl_xor(Bb, 16);
            if (kq & 1) { Bb = fmaf(Aa, oB, Bb); Aa *= oA; }   // mine later
            else        { Bb = fmaf(oA, Bb, oB); Aa *= oA; }   // other later
            oA = __shfl_xor(Aa, 32); oB = __shfl_xor(Bb, 32);
            if (kq & 2) { Bb = fmaf(Aa, oB, Bb); Aa *= oA; }
            else        { Bb = fmaf(oA, Bb, oB); Aa *= oA; }
            if (kq == 0) {
                int d = nt * 128 + wc * 32 + ni * 16 + r;
                int bc = mt * 8 + mi;        // global 16-chunk id = b*NCH + ch
                Ac[(size_t)bc * 1024 + d] = Aa;
                Bc[(size_t)bc * 1024 + d] = Bb;
            }
        }
    }
}

// ========== split-K W_comb GEMM (128x128 tile, r2-validated structure) ==========
__global__ __launch_bounds__(256) void wcomb_splitk(const _Float16* __restrict__ A,
                                                    const _Float16* __restrict__ Bm,
                                                    float* __restrict__ part) {
    __shared__ _Float16 As[128 * 32];
    __shared__ _Float16 Bs[128 * 32];
    int bid = blockIdx.x;                 // mt + 8*nt + 64*slice
    int mt = bid & 7, nt = (bid >> 3) & 7, sl = bid >> 6;
    int m0 = mt * 128, n0 = nt * 128, kbeg = sl * 256;
    int tid = threadIdx.x, wid = tid >> 6, lane = tid & 63;
    int wr = wid >> 1, wc = wid & 1;

    f32x4 acc[4][4];
#pragma unroll
    for (int i = 0; i < 4; i++)
#pragma unroll
        for (int j = 0; j < 4; j++) acc[i][j] = (f32x4)0.f;

    int r = lane & 15, kq = lane >> 4;

    for (int kt = kbeg; kt < kbeg + 256; kt += 32) {
        __syncthreads();
#pragma unroll
        for (int j = 0; j < 2; ++j) {
            int f = j * 256 + tid;
            int row = f >> 2, kc = f & 3;
            gl_lds16(A + (size_t)(m0 + row) * 1024 + kt + kc * 8, As + (size_t)(j * 256 + wid * 64) * 8);
            gl_lds16(Bm + (size_t)(n0 + row) * 1024 + kt + kc * 8, Bs + (size_t)(j * 256 + wid * 64) * 8);
        }
        __syncthreads();
        half8 af[4], bf[4];
#pragma unroll
        for (int mi = 0; mi < 4; mi++) af[mi] = *(const half8*)&As[(wr * 64 + mi * 16 + r) * 32 + kq * 8];
#pragma unroll
        for (int ni = 0; ni < 4; ni++) bf[ni] = *(const half8*)&Bs[(wc * 64 + ni * 16 + r) * 32 + kq * 8];
#pragma unroll
        for (int mi = 0; mi < 4; mi++)
#pragma unroll
            for (int ni = 0; ni < 4; ni++)
                acc[mi][ni] = __builtin_amdgcn_mfma_f32_16x16x32_f16(af[mi], bf[ni], acc[mi][ni], 0, 0, 0);
    }

    int rr = kq * 4;
    float* pbp = part + (size_t)sl * 1048576;
#pragma unroll
    for (int mi = 0; mi < 4; mi++) {
        int mbase = m0 + wr * 64 + mi * 16 + rr;
#pragma unroll
        for (int ni = 0; ni < 4; ni++) {
            int n = n0 + wc * 64 + ni * 16 + r;
#pragma unroll
            for (int q = 0; q < 4; q++)
                pbp[(size_t)(mbase + q) * 1024 + n] = acc[mi][ni][q];
        }
    }
}

// combine 4 split-K slices -> packed comb units (nf 64..127) [r9/r16-validated]
__global__ __launch_bounds__(256) void wcomb_combine_pack(const float* __restrict__ part,
                                                          _Float16* __restrict__ pk) {
    int i = blockIdx.x * 256 + threadIdx.x;   // 0..131071 units
    int ll = i & 63, u = i >> 6;
    int kt = u & 31, nf = u >> 5;             // local nf 0..63
    int e = nf * 16 + (ll & 15);              // W_comb row
    int k = kt * 32 + (ll >> 4) * 8;
    size_t o = (size_t)e * 1024 + k;
    float s[8];
#pragma unroll
    for (int j = 0; j < 8; ++j) s[j] = 0.f;
#pragma unroll
    for (int sl = 0; sl < 4; ++sl) {
        const float4* p = (const float4*)&part[(size_t)sl * 1048576 + o];
        float4 a = p[0], c = p[1];
        s[0] += a.x; s[1] += a.y; s[2] += a.z; s[3] += a.w;
        s[4] += c.x; s[5] += c.y; s[6] += c.z; s[7] += c.w;
    }
    half8 h;
#pragma unroll
    for (int j = 0; j < 8; ++j) h[j] = (_Float16)s[j];
    *(half8*)&pk[1048576 + (size_t)i * 8] = h;   // comb half of packed array
}

// pass 2: sequential over 128 chunks; 64-thread blocks x 256 -> all CUs active.
__global__ __launch_bounds__(64) void scan_pass2(const float* __restrict__ Ac,
                                                 const float* __restrict__ Bc,
                                                 float* __restrict__ h0w) {
    int idx = blockIdx.x * 64 + threadIdx.x;    // b*D + d, 16384 total
    int b = idx >> 10, d = idx & (D_DIM - 1);
    float h = 0.f;
#pragma unroll 8
    for (int ch = 0; ch < NCH; ++ch) {
        size_t k = ((size_t)(b * NCH + ch) << 10) + d;
        float a = Ac[k];
        float bv = Bc[k];
        h0w[k] = h;
        h = fmaf(a, h, bv);
    }
}

// ---- fused scan pass 3 + LayerNorm: 4 waves/chunk (256 dims each, 4/lane),
// ---- depth-2 prefetch, parity-double-buffered cross-wave LN reduce ----
__global__ __launch_bounds__(256) void scan_ln(const _Float16* __restrict__ u,
                                               const _Float16* __restrict__ cd,
                                               const float* __restrict__ h0,
                                               const float* __restrict__ gamma,
                                               const float* __restrict__ beta,
                                               float* __restrict__ outp) {
    int bc = blockIdx.x;                // b*NCH + ch
    int b = bc >> 7, ch = bc & (NCH - 1);
    int tid = threadIdx.x;
    int wv = tid >> 6, lane = tid & 63; // 4 waves
    int d0 = wv * 256 + lane * 4;       // 4 dims/lane
    size_t base = ((size_t)b * T_DIM + (size_t)ch * CHUNK) * D_DIM + d0;

    __shared__ float ls[2][4], lq[2][4];   // [parity][wave]

    float g[4], be[4], h[4];
    *(float4*)&g[0]  = *(const float4*)&gamma[d0];
    *(float4*)&be[0] = *(const float4*)&beta[d0];
    size_t o = (size_t)bc * D_DIM + d0;
    *(float4*)&h[0] = *(const float4*)&h0[o];

    // depth-2 prefetch (one u/cand half4 pair per row per lane)
    half4v ua0 = *(const half4v*)&u[base];
    half4v ca0 = *(const half4v*)&cd[base];
    half4v ua1 = *(const half4v*)&u[base + D_DIM];
    half4v ca1 = *(const half4v*)&cd[base + D_DIM];

#pragma unroll
    for (int t = 0; t < CHUNK; t += 2) {
        half4v nua0, nca0, nua1, nca1;
        if (t + 2 < CHUNK) {
            size_t nrow = base + (size_t)(t + 2) * D_DIM;
            nua0 = *(const half4v*)&u[nrow];
            nca0 = *(const half4v*)&cd[nrow];
        }
        if (t + 3 < CHUNK) {
            size_t nrow = base + (size_t)(t + 3) * D_DIM;
            nua1 = *(const half4v*)&u[nrow];
            nca1 = *(const half4v*)&cd[nrow];
        }
        // ---- row t (even; parity slot 0) ----
        {
            size_t row = base + (size_t)t * D_DIM;
            float s = 0.f, q = 0.f;
#pragma unroll
            for (int j = 0; j < 4; ++j) {
                float ut = (float)ua0[j], ct = (float)ca0[j];
                h[j] = fmaf(ut, h[j] - ct, ct);
                s += h[j]; q += h[j] * h[j];
            }
#pragma unroll
            for (int off = 32; off > 0; off >>= 1) {
                s += __shfl_xor(s, off);
                q += __shfl_xor(q, off);
            }
            if (lane == 0) { ls[0][wv] = s; lq[0][wv] = q; }
            __syncthreads();
            s = ls[0][0] + ls[0][1] + ls[0][2] + ls[0][3];
            q = lq[0][0] + lq[0][1] + lq[0][2] + lq[0][3];
            float mu = s * (1.f / D_DIM);
            float var = q * (1.f / D_DIM) - mu * mu;
            float rs = rsqrtf(var + LN_EPS);
            float o4[4];
#pragma unroll
            for (int j = 0; j < 4; ++j) o4[j] = (h[j] - mu) * rs * g[j] + be[j];
            *(float4*)&outp[row] = *(float4*)&o4[0];
        }
        // ---- row t+1 (odd; parity slot 1) ----
        {
            size_t row = base + (size_t)(t + 1) * D_DIM;
            float s = 0.f, q = 0.f;
#pragma unroll
            for (int j = 0; j < 4; ++j) {
                float ut = (float)ua1[j], ct = (float)ca1[j];
                h[j] = fmaf(ut, h[j] - ct, ct);
                s += h[j]; q += h[j] * h[j];
            }
#pragma unroll
            for (int off = 32; off > 0; off >>= 1) {
                s += __shfl_xor(s, off);
                q += __shfl_xor(q, off);
            }
            if (lane == 0) { ls[1][wv] = s; lq[1][wv] = q; }
            __syncthreads();
            s = ls[1][0] + ls[1][1] + ls[1][2] + ls[1][3];
            q = lq[1][0] + lq[1][1] + lq[1][2] + lq[1][3];
            float mu = s * (1.f / D_DIM);
            float var = q * (1.f / D_DIM) - mu * mu;
            float rs = rsqrtf(var + LN_EPS);
            float o4[4];
#pragma unroll
            for (int j = 0; j < 4; ++j) o4[j] = (h[j] - mu) * rs * g[j] + be[j];
            *(float4*)&outp[row] = *(float4*)&o4[0];
        }
        ua0 = nua0; ca0 = nca0;
        ua1 = nua1; ca1 = nca1;
    }
}

extern "C" void kernel_launch(void* const* d_in, const int* in_sizes, int n_in,
                              void* d_out, int out_size, void* d_ws, size_t ws_size,
                              hipStream_t stream) {
    const float* x       = (const float*)d_in[0];
    const float* W_in    = (const float*)d_in[1];
    const float* W_state = (const float*)d_in[2];
    const float* gamma   = (const float*)d_in[3];
    const float* beta    = (const float*)d_in[4];
    float* out = (float*)d_out;

    char* w = (char*)d_ws;
    size_t off = 0;
    auto carve = [&](size_t bytes) {
        void* p = w + off;
        off += (bytes + 255) & ~(size_t)255;
        return p;
    };
    _Float16* xh   = (_Float16*)carve((size_t)M_TOT * K_DIM * 2);           // 64 MiB
    _Float16* pk   = (_Float16*)carve((size_t)2 * D_DIM * K_DIM * 2);       // 4 MiB packed W
    _Float16* uarr = (_Float16*)carve((size_t)M_TOT * D_DIM * 2);           // 64 MiB
    _Float16* cand = (_Float16*)carve((size_t)M_TOT * D_DIM * 2);           // 64 MiB
    char* scratch  = (char*)carve((size_t)16 * 1024 * 1024);                // 16 MiB shared region
    _Float16* wvxT = (_Float16*)scratch;                                    // 2 MiB (early)
    _Float16* wst  = (_Float16*)(scratch + 2 * 1024 * 1024);                // 2 MiB (early)
    float* Ac = (float*)scratch;                                            // 8 MiB (late)
    float* Bc = (float*)(scratch + 8 * 1024 * 1024);                        // 8 MiB (late)
    float* wpart = (float*)cand;   // 16 MiB fp32 partials; cand dead until main GEMM
    float* h0w = (float*)xh;       // 8 MiB; xh dead after gemm256

    // 1. merged prep (x cvt | gate pack | W_state cvt | W_vx transpose)
    prep_all<<<4096, 256, 0, stream>>>(x, W_in, W_state, xh, pk, wvxT, wst);

    // 2. W_comb = W_state @ W_vx -> packed comb units  (split-K x4)
    wcomb_splitk<<<256, 256, 0, stream>>>(wst, wvxT, wpart);
    wcomb_combine_pack<<<512, 256, 0, stream>>>(wpart, pk);

    // 3. fused projection + sigmoid + scan_pass1 (128-row, BK=64, B direct, 2 blk/CU)
    gemm256<<<2048, 256, 0, stream>>>(xh, pk, uarr, cand, Ac, Bc);

    // 4. cross-chunk scan (all-CU spread) + fused pass3/LN (4 waves/chunk)
    scan_pass2<<<(B_DIM * D_DIM) / 64, 64, 0, stream>>>(Ac, Bc, h0w);
    scan_ln<<<B_DIM * NCH, 256, 0, stream>>>(uarr, cand, h0w, gamma, beta, out);
}